// Round 7
// baseline (4683.128 us; speedup 1.0000x reference)
//
#include <hip/hip_runtime.h>
#include <math.h>

#define D_MODEL 768
#define N_LAYER 8
#define D_INNER 1536
#define D_STATE 16
#define DT_RANK 48
#define D_CONV  4
#define BATCH   4
#define SEQLEN  1024
#define NTOK    (BATCH*SEQLEN)      // 4096 token rows
#define DBC_W   (DT_RANK + 2*D_STATE)  // 80
#define NC      32                  // scan chunks per sequence
#define CHUNK_T (SEQLEN/NC)         // 32 timesteps per chunk
#define XP_KS   8                   // xproj split-K slices
#define XP_KSL  (D_INNER/XP_KS)     // 192 k per slice
#define CONV_TCH 16                 // conv outputs per thread

typedef __attribute__((ext_vector_type(8))) short short8v;   // 8 bf16 (4 VGPRs)
typedef __attribute__((ext_vector_type(4))) float float4v;   // 4 fp32 acc

// Split fp32 into hi+lo bf16 (both RNE).  x ~= hi + lo, |err| ~ 2^-17 |x|.
__device__ __forceinline__ void split_bf16(float x, short& hi, short& lo) {
  unsigned u = __float_as_uint(x);
  unsigned r = (u + 0x7fffu + ((u >> 16) & 1u)) >> 16;
  hi = (short)r;
  float fhi = __uint_as_float(r << 16);
  float xl = x - fhi;
  unsigned u2 = __float_as_uint(xl);
  unsigned r2 = (u2 + 0x7fffu + ((u2 >> 16) & 1u)) >> 16;
  lo = (short)r2;
}

// ---------------------------------------------------------------------------
// Weight split: fp32 [n] -> bf16 hi[n], lo[n].  n4 = n/4, float4-vectorized.
// ---------------------------------------------------------------------------
__global__ __launch_bounds__(256) void split_kernel(
    const float* __restrict__ src, short* __restrict__ hi,
    short* __restrict__ lo, int n4) {
  int stride = gridDim.x * 256;
  for (int i = blockIdx.x * 256 + threadIdx.x; i < n4; i += stride) {
    float4 v = ((const float4*)src)[i];
    short4 h, g;
    split_bf16(v.x, h.x, g.x);
    split_bf16(v.y, h.y, g.y);
    split_bf16(v.z, h.z, g.z);
    split_bf16(v.w, h.w, g.w);
    ((short4*)hi)[i] = h;
    ((short4*)lo)[i] = g;
  }
}

// ---------------------------------------------------------------------------
// LayerNorm + residual update.  One block per token row (768 elems, 256 thr).
// first=1: resid = x + pos.  first=0: resid += hy (prev out_proj output).
// Writes normalized output as split bf16 (hh_hi/hh_lo) for the MFMA GEMM.
// ---------------------------------------------------------------------------
__global__ __launch_bounds__(256) void ln_kernel(
    const float* __restrict__ x, const float* __restrict__ pos,
    float* __restrict__ resid, const float* __restrict__ hy,
    short* __restrict__ hh_hi, short* __restrict__ hh_lo,
    const float* __restrict__ w, const float* __restrict__ b, int first) {
  int row = blockIdx.x;
  int tid = threadIdx.x;
  int base = row * D_MODEL;
  __shared__ float red[256];
  __shared__ float s_mu, s_rs;
  float v[3];
#pragma unroll
  for (int i = 0; i < 3; ++i) {
    int c = tid + i * 256;
    float r;
    if (first) r = x[base + c] + pos[base + c];
    else       r = resid[base + c] + hy[base + c];
    resid[base + c] = r;
    v[i] = r;
  }
  float s = v[0] + v[1] + v[2];
  red[tid] = s; __syncthreads();
  for (int off = 128; off > 0; off >>= 1) {
    if (tid < off) red[tid] += red[tid + off];
    __syncthreads();
  }
  if (tid == 0) s_mu = red[0] / D_MODEL;
  __syncthreads();
  float mu = s_mu;
  float q = 0.f;
#pragma unroll
  for (int i = 0; i < 3; ++i) { float d = v[i] - mu; q += d * d; }
  __syncthreads();
  red[tid] = q; __syncthreads();
  for (int off = 128; off > 0; off >>= 1) {
    if (tid < off) red[tid] += red[tid + off];
    __syncthreads();
  }
  if (tid == 0) s_rs = rsqrtf(red[0] / D_MODEL + 1e-5f);
  __syncthreads();
  float rs = s_rs;
#pragma unroll
  for (int i = 0; i < 3; ++i) {
    int c = tid + i * 256;
    float val = (v[i] - mu) * rs * w[c] + b[c];
    short hv, lv; split_bf16(val, hv, lv);
    hh_hi[base + c] = hv;
    hh_lo[base + c] = lv;
  }
}

// ---------------------------------------------------------------------------
// bf16x3 MFMA GEMM:  C[M][N] = A[M][K] . B[N][K]^T  (fp32-equivalent accuracy)
// A,B given as split bf16 (hi,lo).  Computes hi*hi + hi*lo + lo*hi.
// 128x128 tile, BK=32, 256 thr = 4 waves (2x2), 4x4 16x16x32 frags per wave.
// LDS: stride-48 rows (96 B) + 16B-slot XOR swizzle (slot ^= (row>>2)&3):
//   both ds_write and ds_read patterns are exactly 2-way per 16-lane group
//   (free).  Register-prefetch double buffer hides global latency under MFMA.
// XCD-chunked block swizzle for L2 locality (requires grid blocks % 8 == 0).
// ---------------------------------------------------------------------------
__global__ __launch_bounds__(256) void gemm_bf16x3(
    const short* __restrict__ Ahi, const short* __restrict__ Alo, int lda,
    const short* __restrict__ Bhi, const short* __restrict__ Blo, int ldb,
    float* __restrict__ C, int M, int N, int K) {
  const int BK = 32, LDSS = 48;
  __shared__ short Ash[128][LDSS];
  __shared__ short Asl[128][LDSS];
  __shared__ short Bsh[128][LDSS];
  __shared__ short Bsl[128][LDSS];
  // XCD-chunked swizzle (bijective when nb % 8 == 0)
  int gx = gridDim.x;
  int nb = gx * gridDim.y;
  int lin = blockIdx.y * gx + blockIdx.x;
  int nlin = (lin & 7) * (nb >> 3) + (lin >> 3);
  int brow = (nlin / gx) * 128;
  int bcol = (nlin % gx) * 128;
  int tid = threadIdx.x;
  int w = tid >> 6, l = tid & 63;
  int wr = (w >> 1) * 64;            // wave row origin in tile
  int wc = (w & 1) * 64;             // wave col origin in tile
  int lrow = l & 15;
  int rslot = ((l >> 4) ^ (lrow >> 2)) * 8;   // swizzled read slot (shorts)
  float4v zero = {0.f, 0.f, 0.f, 0.f};
  float4v acc[4][4];
#pragma unroll
  for (int m = 0; m < 4; ++m)
#pragma unroll
    for (int n = 0; n < 4; ++n) acc[m][n] = zero;

  uint4 ra_h[2], ra_l[2], rb_h[2], rb_l[2];
#pragma unroll
  for (int it = 0; it < 2; ++it) {           // prefetch tile 0
    int idx = tid + it * 256;
    int r = idx >> 2, s = idx & 3;
    size_t ao = (size_t)(brow + r) * lda + s * 8;
    size_t bo = (size_t)(bcol + r) * ldb + s * 8;
    ra_h[it] = *(const uint4*)&Ahi[ao];
    ra_l[it] = *(const uint4*)&Alo[ao];
    rb_h[it] = *(const uint4*)&Bhi[bo];
    rb_l[it] = *(const uint4*)&Blo[bo];
  }

  for (int k0 = 0; k0 < K; k0 += BK) {
    // write prefetched tile to LDS (swizzled slot)
#pragma unroll
    for (int it = 0; it < 2; ++it) {
      int idx = tid + it * 256;
      int r = idx >> 2, s = idx & 3;
      int sp = (s ^ ((r >> 2) & 3)) * 8;
      *(uint4*)&Ash[r][sp] = ra_h[it];
      *(uint4*)&Asl[r][sp] = ra_l[it];
      *(uint4*)&Bsh[r][sp] = rb_h[it];
      *(uint4*)&Bsl[r][sp] = rb_l[it];
    }
    __syncthreads();
    if (k0 + BK < K) {                       // issue next-tile loads (in flight)
#pragma unroll
      for (int it = 0; it < 2; ++it) {
        int idx = tid + it * 256;
        int r = idx >> 2, s = idx & 3;
        size_t ao = (size_t)(brow + r) * lda + k0 + BK + s * 8;
        size_t bo = (size_t)(bcol + r) * ldb + k0 + BK + s * 8;
        ra_h[it] = *(const uint4*)&Ahi[ao];
        ra_l[it] = *(const uint4*)&Alo[ao];
        rb_h[it] = *(const uint4*)&Bhi[bo];
        rb_l[it] = *(const uint4*)&Blo[bo];
      }
    }
    short8v ah[4], al[4];
#pragma unroll
    for (int m = 0; m < 4; ++m) {
      int R = wr + m * 16 + lrow;
      ah[m] = *(const short8v*)&Ash[R][rslot];
      al[m] = *(const short8v*)&Asl[R][rslot];
    }
#pragma unroll
    for (int n = 0; n < 4; ++n) {
      int R = wc + n * 16 + lrow;
      short8v bh = *(const short8v*)&Bsh[R][rslot];
      short8v bl = *(const short8v*)&Bsl[R][rslot];
#pragma unroll
      for (int m = 0; m < 4; ++m) {
        acc[m][n] = __builtin_amdgcn_mfma_f32_16x16x32_bf16(ah[m], bh, acc[m][n], 0, 0, 0);
        acc[m][n] = __builtin_amdgcn_mfma_f32_16x16x32_bf16(ah[m], bl, acc[m][n], 0, 0, 0);
        acc[m][n] = __builtin_amdgcn_mfma_f32_16x16x32_bf16(al[m], bh, acc[m][n], 0, 0, 0);
      }
    }
    __syncthreads();
  }
  int drow = (l >> 4) * 4, dcol = l & 15;
#pragma unroll
  for (int m = 0; m < 4; ++m)
#pragma unroll
    for (int n = 0; n < 4; ++n)
#pragma unroll
      for (int j = 0; j < 4; ++j)
        C[(size_t)(brow + wr + m * 16 + drow + j) * N + bcol + wc + n * 16 + dcol] =
            acc[m][n][j];
}

// ---------------------------------------------------------------------------
// C[M x N] = A[M x K] * B[N x K]^T   (row-major, fp32, leading dims lda/ldb)
// Used only for the small dt projection (K=48).
// ---------------------------------------------------------------------------
__global__ __launch_bounds__(256) void gemm_abt(
    const float* __restrict__ A, int lda, const float* __restrict__ B, int ldb,
    float* __restrict__ C, int M, int N, int K) {
  const int BM = 128, BN = 128, BK = 16;
  __shared__ __align__(16) float As[BK][BM + 4];
  __shared__ __align__(16) float Bs[BK][BN + 4];
  int brow = blockIdx.y * BM;
  int bcol = blockIdx.x * BN;
  int tid = threadIdx.x;
  int tr = (tid / 16) * 4;   // 0..60
  int tc = (tid % 16) * 4;   // 0..60
  float acc[2][2][4][4] = {};   // [row-half][col-half][i][j]
  for (int k0 = 0; k0 < K; k0 += BK) {
#pragma unroll
    for (int it = 0; it < 2; ++it) {
      int idx = tid + it * 256;          // 0..511
      int r  = idx >> 2;                 // 0..127
      int cq = (idx & 3) * 4;            // 0,4,8,12
      float4 a = *(const float4*)&A[(size_t)(brow + r) * lda + k0 + cq];
      As[cq + 0][r] = a.x; As[cq + 1][r] = a.y;
      As[cq + 2][r] = a.z; As[cq + 3][r] = a.w;
      float4 b = *(const float4*)&B[(size_t)(bcol + r) * ldb + k0 + cq];
      Bs[cq + 0][r] = b.x; Bs[cq + 1][r] = b.y;
      Bs[cq + 2][r] = b.z; Bs[cq + 3][r] = b.w;
    }
    __syncthreads();
#pragma unroll
    for (int kk = 0; kk < BK; ++kk) {
      float4 a0 = *(const float4*)&As[kk][tr];
      float4 a1 = *(const float4*)&As[kk][tr + 64];
      float4 b0 = *(const float4*)&Bs[kk][tc];
      float4 b1 = *(const float4*)&Bs[kk][tc + 64];
      float ar[2][4] = {{a0.x, a0.y, a0.z, a0.w}, {a1.x, a1.y, a1.z, a1.w}};
      float br[2][4] = {{b0.x, b0.y, b0.z, b0.w}, {b1.x, b1.y, b1.z, b1.w}};
#pragma unroll
      for (int rh = 0; rh < 2; ++rh)
#pragma unroll
        for (int ch = 0; ch < 2; ++ch)
#pragma unroll
          for (int i = 0; i < 4; ++i)
#pragma unroll
            for (int j = 0; j < 4; ++j)
              acc[rh][ch][i][j] += ar[rh][i] * br[ch][j];
    }
    __syncthreads();
  }
#pragma unroll
  for (int rh = 0; rh < 2; ++rh)
#pragma unroll
    for (int i = 0; i < 4; ++i) {
      int row = brow + tr + rh * 64 + i;
#pragma unroll
      for (int ch = 0; ch < 2; ++ch) {
        float4 o = make_float4(acc[rh][ch][i][0], acc[rh][ch][i][1],
                               acc[rh][ch][i][2], acc[rh][ch][i][3]);
        *(float4*)&C[(size_t)row * N + bcol + tc + ch * 64] = o;
      }
    }
}

// ---------------------------------------------------------------------------
// part[slice][M=4096][80] = u[.,kslice] . xp[.,kslice]^T  (split-K, no atomics)
// blockIdx.x: 64-row tile; blockIdx.y: K-slice of 192.  512 blocks total.
// ---------------------------------------------------------------------------
__global__ __launch_bounds__(256) void xproj_gemm(
    const float* __restrict__ u, const float* __restrict__ xp,
    float* __restrict__ part) {
  const int BM = 64, BK = 64;
  __shared__ float As[BK][BM + 1];     // stride 65
  __shared__ float Bs[BK][DBC_W + 1];  // stride 81
  int brow = blockIdx.x * BM;
  int kbase = blockIdx.y * XP_KSL;
  int tid = threadIdx.x;
  int tr = (tid / 16) * 4;    // 0..60
  int tc = (tid % 16) * 5;    // 0..75
  float acc[4][5] = {};
  for (int k0 = kbase; k0 < kbase + XP_KSL; k0 += BK) {
#pragma unroll
    for (int it = 0; it < 4; ++it) {           // A: 64 rows x 64 k
      int lin = tid + it * 256;                // 0..1023
      int r  = lin >> 4;                       // 0..63
      int kq = (lin & 15) * 4;
      float4 a = *(const float4*)&u[(size_t)(brow + r) * D_INNER + k0 + kq];
      As[kq + 0][r] = a.x; As[kq + 1][r] = a.y;
      As[kq + 2][r] = a.z; As[kq + 3][r] = a.w;
    }
#pragma unroll
    for (int it = 0; it < 5; ++it) {           // B: 80 rows x 64 k
      int lin = tid + it * 256;                // 0..1279
      int e  = lin >> 4;                       // 0..79
      int kq = (lin & 15) * 4;
      float4 b = *(const float4*)&xp[(size_t)e * D_INNER + k0 + kq];
      Bs[kq + 0][e] = b.x; Bs[kq + 1][e] = b.y;
      Bs[kq + 2][e] = b.z; Bs[kq + 3][e] = b.w;
    }
    __syncthreads();
#pragma unroll
    for (int kk = 0; kk < BK; ++kk) {
      float ar[4], br[5];
#pragma unroll
      for (int i = 0; i < 4; ++i) ar[i] = As[kk][tr + i];
#pragma unroll
      for (int j = 0; j < 5; ++j) br[j] = Bs[kk][tc + j];
#pragma unroll
      for (int i = 0; i < 4; ++i)
#pragma unroll
        for (int j = 0; j < 5; ++j) acc[i][j] += ar[i] * br[j];
    }
    __syncthreads();
  }
  float* dst = part + (size_t)blockIdx.y * NTOK * DBC_W;
#pragma unroll
  for (int i = 0; i < 4; ++i)
#pragma unroll
    for (int j = 0; j < 5; ++j)
      dst[(size_t)(brow + tr + i) * DBC_W + tc + j] = acc[i][j];
}

// ---------------------------------------------------------------------------
// dbc = sum over XP_KS slices of part.  float4-vectorized.
// ---------------------------------------------------------------------------
__global__ __launch_bounds__(256) void reduce_dbc_kernel(
    const float* __restrict__ part, float* __restrict__ dbc, int n4) {
  int i = blockIdx.x * 256 + threadIdx.x;
  if (i >= n4) return;
  float4 s = ((const float4*)part)[i];
#pragma unroll
  for (int k = 1; k < XP_KS; ++k) {
    float4 v = ((const float4*)(part + (size_t)k * NTOK * DBC_W))[i];
    s.x += v.x; s.y += v.y; s.z += v.z; s.w += v.w;
  }
  ((float4*)dbc)[i] = s;
}

// ---------------------------------------------------------------------------
// Causal depthwise conv (width 4) + bias + SiLU, rolling-window form.
// One thread per (b, t-chunk of 16, c): 19 loads -> 16 outputs (vs 4 loads
// per output in the naive form).  t0 is a multiple of 16 so the 3-tap
// history is either fully valid (t0>0) or all zero (t0==0).
// ---------------------------------------------------------------------------
__global__ __launch_bounds__(256) void conv_silu_kernel(
    const float* __restrict__ xz, const float* __restrict__ cw,
    const float* __restrict__ cb, float* __restrict__ u) {
  int idx = blockIdx.x * 256 + threadIdx.x;
  const int NTC = SEQLEN / CONV_TCH;
  if (idx >= BATCH * NTC * D_INNER) return;
  int c  = idx % D_INNER;
  int tc = (idx / D_INNER) % NTC;
  int b  = idx / (D_INNER * NTC);
  int t0 = tc * CONV_TCH;
  float w0 = cw[c * 4 + 0], w1 = cw[c * 4 + 1];
  float w2 = cw[c * 4 + 2], w3 = cw[c * 4 + 3];
  float bias = cb[c];
  const float* base = xz + (size_t)b * SEQLEN * (2 * D_INNER) + c;
  float xm3 = 0.f, xm2 = 0.f, xm1 = 0.f;
  if (t0 > 0) {
    xm3 = base[(size_t)(t0 - 3) * (2 * D_INNER)];
    xm2 = base[(size_t)(t0 - 2) * (2 * D_INNER)];
    xm1 = base[(size_t)(t0 - 1) * (2 * D_INNER)];
  }
  float* ub = u + (size_t)(b * SEQLEN + t0) * D_INNER + c;
#pragma unroll
  for (int i = 0; i < CONV_TCH; ++i) {
    float xt = base[(size_t)(t0 + i) * (2 * D_INNER)];
    float acc = bias + xm3 * w0 + xm2 * w1 + xm1 * w2 + xt * w3;
    float sig = 1.f / (1.f + __expf(-acc));
    ub[(size_t)i * D_INNER] = acc * sig;
    xm3 = xm2; xm2 = xm1; xm1 = xt;
  }
}

__device__ __forceinline__ float softplusf(float a) {
  return (a > 20.f) ? a : log1pf(__expf(a));
}

// ---------------------------------------------------------------------------
// Blocked selective scan, phase 1.  dty holds RAW dt scores (pre-bias,
// pre-softplus); bias+softplus applied here on the fly.
// ---------------------------------------------------------------------------
__global__ __launch_bounds__(256) void scan_chunk1(
    const float* __restrict__ dty, const float* __restrict__ u,
    const float* __restrict__ dbc, const float* __restrict__ A_log,
    const float* __restrict__ dtb,
    float* __restrict__ S, float* __restrict__ dtsum) {
  int g = blockIdx.x * 256 + threadIdx.x;
  if (g >= BATCH * NC * D_INNER) return;
  int d = g % D_INNER;
  int c = (g / D_INNER) % NC;
  int b = g / (D_INNER * NC);
  float A[D_STATE];
#pragma unroll
  for (int s = 0; s < D_STATE; ++s) A[s] = -__expf(A_log[d * D_STATE + s]);
  float bias = dtb[d];
  float h[D_STATE];
#pragma unroll
  for (int s = 0; s < D_STATE; ++s) h[s] = 0.f;
  float dts = 0.f;
  int t0 = c * CHUNK_T;
  for (int t = t0; t < t0 + CHUNK_T; ++t) {
    size_t rowb = (size_t)b * SEQLEN + t;
    float dtv = softplusf(dty[rowb * D_INNER + d] + bias);
    float uv  = u[rowb * D_INNER + d];
    const float* bc = dbc + rowb * DBC_W;
    float dtu = dtv * uv;
    dts += dtv;
#pragma unroll
    for (int s = 0; s < D_STATE; ++s) {
      float da = __expf(dtv * A[s]);
      h[s] = da * h[s] + dtu * bc[DT_RANK + s];
    }
  }
  size_t base = (((size_t)b * NC + c) * D_STATE) * D_INNER + d;
#pragma unroll
  for (int s = 0; s < D_STATE; ++s) S[base + (size_t)s * D_INNER] = h[s];
  dtsum[((size_t)b * NC + c) * D_INNER + d] = dts;
}

// ---------------------------------------------------------------------------
// Blocked selective scan, phase 2 (serial chunk combine, tiny).
// ---------------------------------------------------------------------------
__global__ __launch_bounds__(256) void scan_combine(
    float* __restrict__ S, const float* __restrict__ dtsum,
    const float* __restrict__ A_log) {
  int g = blockIdx.x * 256 + threadIdx.x;
  if (g >= BATCH * D_INNER) return;
  int b = g / D_INNER, d = g % D_INNER;
  float A[D_STATE];
#pragma unroll
  for (int s = 0; s < D_STATE; ++s) A[s] = -__expf(A_log[d * D_STATE + s]);
  float h[D_STATE];
#pragma unroll
  for (int s = 0; s < D_STATE; ++s) h[s] = 0.f;
  for (int c = 0; c < NC; ++c) {
    size_t base = (((size_t)b * NC + c) * D_STATE) * D_INNER + d;
    float dts = dtsum[((size_t)b * NC + c) * D_INNER + d];
#pragma unroll
    for (int s = 0; s < D_STATE; ++s) {
      size_t off = base + (size_t)s * D_INNER;
      float Sv = S[off];
      S[off] = h[s];                       // h_in for chunk c
      h[s] = __expf(dts * A[s]) * h[s] + Sv;
    }
  }
}

// ---------------------------------------------------------------------------
// Blocked selective scan, phase 3.  Applies bias+softplus to raw dt,
// computes y, D-skip, SiLU(z) gating; writes gated y as split bf16.
// ---------------------------------------------------------------------------
__global__ __launch_bounds__(256) void scan_chunk2(
    const float* __restrict__ dty, const float* __restrict__ u,
    const float* __restrict__ dbc, const float* __restrict__ xz,
    const float* __restrict__ A_log, const float* __restrict__ dtb,
    const float* __restrict__ Dv, const float* __restrict__ hin,
    short* __restrict__ y_hi, short* __restrict__ y_lo) {
  int g = blockIdx.x * 256 + threadIdx.x;
  if (g >= BATCH * NC * D_INNER) return;
  int d = g % D_INNER;
  int c = (g / D_INNER) % NC;
  int b = g / (D_INNER * NC);
  float A[D_STATE];
#pragma unroll
  for (int s = 0; s < D_STATE; ++s) A[s] = -__expf(A_log[d * D_STATE + s]);
  float bias = dtb[d];
  float Dval = Dv[d];
  float h[D_STATE];
  size_t hbase = (((size_t)b * NC + c) * D_STATE) * D_INNER + d;
#pragma unroll
  for (int s = 0; s < D_STATE; ++s) h[s] = hin[hbase + (size_t)s * D_INNER];
  int t0 = c * CHUNK_T;
  for (int t = t0; t < t0 + CHUNK_T; ++t) {
    size_t rowb = (size_t)b * SEQLEN + t;
    float dtv = softplusf(dty[rowb * D_INNER + d] + bias);
    float uv  = u[rowb * D_INNER + d];
    const float* bc = dbc + rowb * DBC_W;
    float dtu = dtv * uv;
    float yv = 0.f;
#pragma unroll
    for (int s = 0; s < D_STATE; ++s) {
      float da = __expf(dtv * A[s]);
      h[s] = da * h[s] + dtu * bc[DT_RANK + s];
      yv += h[s] * bc[DT_RANK + D_STATE + s];
    }
    float zv = xz[rowb * (2 * D_INNER) + D_INNER + d];
    float sig = 1.f / (1.f + __expf(-zv));
    float yo = (yv + uv * Dval) * (zv * sig);
    short hv, lv; split_bf16(yo, hv, lv);
    y_hi[rowb * D_INNER + d] = hv;
    y_lo[rowb * D_INNER + d] = lv;
  }
}

// ---------------------------------------------------------------------------
// Final: residual add + LN(normf) + LN(dec), last rtn tokens only.
// ---------------------------------------------------------------------------
__global__ __launch_bounds__(256) void final_kernel(
    const float* __restrict__ hy, const float* __restrict__ resid,
    const float* __restrict__ fw, const float* __restrict__ fb,
    const float* __restrict__ dw, const float* __restrict__ db,
    float* __restrict__ out, int rtn) {
  int rowo = blockIdx.x;                 // 0 .. BATCH*rtn-1
  int b = rowo / rtn;
  int t = SEQLEN - rtn + (rowo % rtn);
  int tid = threadIdx.x;
  size_t base = ((size_t)b * SEQLEN + t) * D_MODEL;
  __shared__ float red[256];
  __shared__ float s_mu1, s_rs1, s_mu2, s_rs2;
  float v[3];
#pragma unroll
  for (int i = 0; i < 3; ++i) {
    int c = tid + i * 256;
    v[i] = hy[base + c] + resid[base + c];
  }
  // --- LN 1 ---
  red[tid] = v[0] + v[1] + v[2]; __syncthreads();
  for (int off = 128; off > 0; off >>= 1) {
    if (tid < off) red[tid] += red[tid + off];
    __syncthreads();
  }
  if (tid == 0) s_mu1 = red[0] / D_MODEL;
  __syncthreads();
  float mu = s_mu1, q = 0.f;
#pragma unroll
  for (int i = 0; i < 3; ++i) { float dd = v[i] - mu; q += dd * dd; }
  __syncthreads();
  red[tid] = q; __syncthreads();
  for (int off = 128; off > 0; off >>= 1) {
    if (tid < off) red[tid] += red[tid + off];
    __syncthreads();
  }
  if (tid == 0) s_rs1 = rsqrtf(red[0] / D_MODEL + 1e-5f);
  __syncthreads();
  float rs = s_rs1;
#pragma unroll
  for (int i = 0; i < 3; ++i) {
    int c = tid + i * 256;
    v[i] = (v[i] - mu) * rs * fw[c] + fb[c];
  }
  // --- LN 2 ---
  __syncthreads();
  red[tid] = v[0] + v[1] + v[2]; __syncthreads();
  for (int off = 128; off > 0; off >>= 1) {
    if (tid < off) red[tid] += red[tid + off];
    __syncthreads();
  }
  if (tid == 0) s_mu2 = red[0] / D_MODEL;
  __syncthreads();
  mu = s_mu2; q = 0.f;
#pragma unroll
  for (int i = 0; i < 3; ++i) { float dd = v[i] - mu; q += dd * dd; }
  __syncthreads();
  red[tid] = q; __syncthreads();
  for (int off = 128; off > 0; off >>= 1) {
    if (tid < off) red[tid] += red[tid + off];
    __syncthreads();
  }
  if (tid == 0) s_rs2 = rsqrtf(red[0] / D_MODEL + 1e-5f);
  __syncthreads();
  rs = s_rs2;
#pragma unroll
  for (int i = 0; i < 3; ++i) {
    int c = tid + i * 256;
    out[(size_t)rowo * D_MODEL + c] = (v[i] - mu) * rs * dw[c] + db[c];
  }
}

// ---------------------------------------------------------------------------
extern "C" void kernel_launch(void* const* d_in, const int* in_sizes, int n_in,
                              void* d_out, int out_size, void* d_ws, size_t ws_size,
                              hipStream_t stream) {
  const float* x       = (const float*)d_in[0];
  const float* pos     = (const float*)d_in[1];
  const float* norm_w  = (const float*)d_in[2];
  const float* norm_b  = (const float*)d_in[3];
  const float* in_proj = (const float*)d_in[4];
  const float* conv_w  = (const float*)d_in[5];
  const float* conv_b  = (const float*)d_in[6];
  const float* x_proj  = (const float*)d_in[7];
  const float* dt_w    = (const float*)d_in[8];
  const float* dt_b    = (const float*)d_in[9];
  const float* A_log   = (const float*)d_in[10];
  const float* Dv      = (const float*)d_in[11];
  const float* out_proj= (const float*)d_in[12];
  const float* normf_w = (const float*)d_in[13];
  const float* normf_b = (const float*)d_in[14];
  const float* dec_w   = (const float*)d_in[15];
  const float* dec_b   = (const float*)d_in[16];
  int rtn = out_size / (BATCH * D_MODEL);   // return_token_num

  float* ws    = (float*)d_ws;
  float* resid = ws;                                 // NTOK*D_MODEL
  float* hy    = resid + (size_t)NTOK * D_MODEL;     // NTOK*D_MODEL (out_proj out)
  float* xz    = hy    + (size_t)NTOK * D_MODEL;     // NTOK*2*D_INNER
  float* u     = xz    + (size_t)NTOK * 2 * D_INNER; // NTOK*D_INNER
  float* dbc   = u     + (size_t)NTOK * D_INNER;     // NTOK*80
  float* dty   = dbc   + (size_t)NTOK * DBC_W;       // NTOK*D_INNER (raw dt)
  float* Sbuf  = dty   + (size_t)NTOK * D_INNER;     // BATCH*NC*D_STATE*D_INNER
  float* dtsum = Sbuf  + (size_t)BATCH * NC * D_STATE * D_INNER; // BATCH*NC*D_INNER
  float* dbcp  = dtsum + (size_t)BATCH * NC * D_INNER; // XP_KS*NTOK*DBC_W
  short* hh_hi = (short*)(dbcp + (size_t)XP_KS * NTOK * DBC_W);
  short* hh_lo = hh_hi + (size_t)NTOK * D_MODEL;
  short* y_hi  = hh_lo + (size_t)NTOK * D_MODEL;
  short* y_lo  = y_hi  + (size_t)NTOK * D_INNER;
  short* wbh   = y_lo  + (size_t)NTOK * D_INNER;     // 2*D_INNER*D_MODEL shorts
  short* wbl   = wbh   + (size_t)2 * D_INNER * D_MODEL;

  for (int l = 0; l < N_LAYER; ++l) {
    // split in_proj weights for this layer -> wbh/wbl
    split_kernel<<<1024, 256, 0, stream>>>(
        in_proj + (size_t)l * 2 * D_INNER * D_MODEL, wbh, wbl,
        2 * D_INNER * D_MODEL / 4);

    ln_kernel<<<NTOK, 256, 0, stream>>>(x, pos, resid, hy, hh_hi, hh_lo,
        norm_w + l * D_MODEL, norm_b + l * D_MODEL, l == 0);

    dim3 g1(2 * D_INNER / 128, NTOK / 128);
    gemm_bf16x3<<<g1, 256, 0, stream>>>(hh_hi, hh_lo, D_MODEL,
        wbh, wbl, D_MODEL, xz, NTOK, 2 * D_INNER, D_MODEL);

    int convtot = BATCH * (SEQLEN / CONV_TCH) * D_INNER;
    conv_silu_kernel<<<(convtot + 255) / 256, 256, 0, stream>>>(
        xz, conv_w + (size_t)l * D_INNER * D_CONV, conv_b + l * D_INNER, u);

    dim3 gxp(NTOK / 64, XP_KS);
    xproj_gemm<<<gxp, 256, 0, stream>>>(
        u, x_proj + (size_t)l * DBC_W * D_INNER, dbcp);
    reduce_dbc_kernel<<<(NTOK * DBC_W / 4 + 255) / 256, 256, 0, stream>>>(
        dbcp, dbc, NTOK * DBC_W / 4);

    // dt raw scores: dbc[:, :48] @ dt_w^T  -> dty   (M=4096, N=1536, K=48)
    dim3 gdt(D_INNER / 128, NTOK / 128);
    gemm_abt<<<gdt, 256, 0, stream>>>(dbc, DBC_W,
        dt_w + (size_t)l * D_INNER * DT_RANK, DT_RANK, dty,
        NTOK, D_INNER, DT_RANK);

    const float* Al = A_log + (size_t)l * D_INNER * D_STATE;
    const float* dtbl = dt_b + (size_t)l * D_INNER;
    int tot1 = BATCH * NC * D_INNER;
    scan_chunk1<<<(tot1 + 255) / 256, 256, 0, stream>>>(
        dty, u, dbc, Al, dtbl, Sbuf, dtsum);
    scan_combine<<<(BATCH * D_INNER + 255) / 256, 256, 0, stream>>>(
        Sbuf, dtsum, Al);
    scan_chunk2<<<(tot1 + 255) / 256, 256, 0, stream>>>(
        dty, u, dbc, xz, Al, dtbl, Dv + l * D_INNER, Sbuf, y_hi, y_lo);

    // split out_proj weights for this layer -> wbh/wbl (reuse buffer)
    split_kernel<<<1024, 256, 0, stream>>>(
        out_proj + (size_t)l * D_MODEL * D_INNER, wbh, wbl,
        D_MODEL * D_INNER / 4);

    dim3 g2(D_MODEL / 128, NTOK / 128);
    gemm_bf16x3<<<g2, 256, 0, stream>>>(y_hi, y_lo, D_INNER,
        wbh, wbl, D_INNER, hy, NTOK, D_MODEL, D_INNER);
  }

  final_kernel<<<BATCH * rtn, 256, 0, stream>>>(
      hy, resid, normf_w, normf_b, dec_w, dec_b, (float*)d_out, rtn);
}

// Round 8
// 3011.036 us; speedup vs baseline: 1.5553x; 1.5553x over previous
//
#include <hip/hip_runtime.h>
#include <math.h>

#define D_MODEL 768
#define N_LAYER 8
#define D_INNER 1536
#define D_STATE 16
#define DT_RANK 48
#define D_CONV  4
#define BATCH   4
#define SEQLEN  1024
#define NTOK    (BATCH*SEQLEN)      // 4096 token rows
#define DBC_W   (DT_RANK + 2*D_STATE)  // 80
#define NC      32                  // scan chunks per sequence
#define CHUNK_T (SEQLEN/NC)         // 32 timesteps per chunk
#define XP_KS   8                   // xproj split-K slices
#define XP_KSL  (D_INNER/XP_KS)     // 192 k per slice
#define CONV_TCH 16                 // conv outputs per thread

typedef __attribute__((ext_vector_type(8))) short short8v;   // 8 bf16 (4 VGPRs)
typedef __attribute__((ext_vector_type(4))) float float4v;   // 4 fp32 acc

// Split fp32 into hi+lo bf16 (both RNE).  x ~= hi + lo, |err| ~ 2^-17 |x|.
__device__ __forceinline__ void split_bf16(float x, short& hi, short& lo) {
  unsigned u = __float_as_uint(x);
  unsigned r = (u + 0x7fffu + ((u >> 16) & 1u)) >> 16;
  hi = (short)r;
  float fhi = __uint_as_float(r << 16);
  float xl = x - fhi;
  unsigned u2 = __float_as_uint(xl);
  unsigned r2 = (u2 + 0x7fffu + ((u2 >> 16) & 1u)) >> 16;
  lo = (short)r2;
}

// ---------------------------------------------------------------------------
// Weight split: fp32 [n] -> bf16 hi[n], lo[n].  n4 = n/4, float4-vectorized.
// ---------------------------------------------------------------------------
__global__ __launch_bounds__(256) void split_kernel(
    const float* __restrict__ src, short* __restrict__ hi,
    short* __restrict__ lo, int n4) {
  int stride = gridDim.x * 256;
  for (int i = blockIdx.x * 256 + threadIdx.x; i < n4; i += stride) {
    float4 v = ((const float4*)src)[i];
    short4 h, g;
    split_bf16(v.x, h.x, g.x);
    split_bf16(v.y, h.y, g.y);
    split_bf16(v.z, h.z, g.z);
    split_bf16(v.w, h.w, g.w);
    ((short4*)hi)[i] = h;
    ((short4*)lo)[i] = g;
  }
}

// ---------------------------------------------------------------------------
// LayerNorm + residual update.  One block per token row (768 elems, 256 thr).
// first=1: resid = x + pos.  first=0: resid += hy (prev out_proj output).
// Writes normalized output as split bf16 (hh_hi/hh_lo) for the MFMA GEMM.
// ---------------------------------------------------------------------------
__global__ __launch_bounds__(256) void ln_kernel(
    const float* __restrict__ x, const float* __restrict__ pos,
    float* __restrict__ resid, const float* __restrict__ hy,
    short* __restrict__ hh_hi, short* __restrict__ hh_lo,
    const float* __restrict__ w, const float* __restrict__ b, int first) {
  int row = blockIdx.x;
  int tid = threadIdx.x;
  int base = row * D_MODEL;
  __shared__ float red[256];
  __shared__ float s_mu, s_rs;
  float v[3];
#pragma unroll
  for (int i = 0; i < 3; ++i) {
    int c = tid + i * 256;
    float r;
    if (first) r = x[base + c] + pos[base + c];
    else       r = resid[base + c] + hy[base + c];
    resid[base + c] = r;
    v[i] = r;
  }
  float s = v[0] + v[1] + v[2];
  red[tid] = s; __syncthreads();
  for (int off = 128; off > 0; off >>= 1) {
    if (tid < off) red[tid] += red[tid + off];
    __syncthreads();
  }
  if (tid == 0) s_mu = red[0] / D_MODEL;
  __syncthreads();
  float mu = s_mu;
  float q = 0.f;
#pragma unroll
  for (int i = 0; i < 3; ++i) { float d = v[i] - mu; q += d * d; }
  __syncthreads();
  red[tid] = q; __syncthreads();
  for (int off = 128; off > 0; off >>= 1) {
    if (tid < off) red[tid] += red[tid + off];
    __syncthreads();
  }
  if (tid == 0) s_rs = rsqrtf(red[0] / D_MODEL + 1e-5f);
  __syncthreads();
  float rs = s_rs;
#pragma unroll
  for (int i = 0; i < 3; ++i) {
    int c = tid + i * 256;
    float val = (v[i] - mu) * rs * w[c] + b[c];
    short hv, lv; split_bf16(val, hv, lv);
    hh_hi[base + c] = hv;
    hh_lo[base + c] = lv;
  }
}

// ---------------------------------------------------------------------------
// bf16x3 MFMA GEMM:  C[M][N] = A[M][K] . B[N][K]^T  (fp32-equivalent accuracy)
// A,B given as split bf16 (hi,lo).  Computes hi*hi + hi*lo + lo*hi.
// 128x128 tile, BK=32, 256 thr = 4 waves (2x2), 4x4 16x16x32 frags per wave.
// Direct global->LDS staging (NO register prefetch: round-7's reg-prefetch
// arrays were demoted to scratch -> 600 MB spill traffic, 2.4x slower).
// LDS: stride-48 rows + 16B-slot XOR swizzle (slot ^= (row>>2)&3) -- halves
// bank conflicts vs stride-40 (measured 9.4M -> 4.7M).
// XCD-chunked block swizzle for L2 locality (requires grid blocks % 8 == 0).
// ---------------------------------------------------------------------------
__global__ __launch_bounds__(256) void gemm_bf16x3(
    const short* __restrict__ Ahi, const short* __restrict__ Alo, int lda,
    const short* __restrict__ Bhi, const short* __restrict__ Blo, int ldb,
    float* __restrict__ C, int M, int N, int K) {
  const int BK = 32, LDSS = 48;
  __shared__ short Ash[128][LDSS];
  __shared__ short Asl[128][LDSS];
  __shared__ short Bsh[128][LDSS];
  __shared__ short Bsl[128][LDSS];
  // XCD-chunked swizzle (bijective when nb % 8 == 0)
  int gx = gridDim.x;
  int nb = gx * gridDim.y;
  int lin = blockIdx.y * gx + blockIdx.x;
  int nlin = (lin & 7) * (nb >> 3) + (lin >> 3);
  int brow = (nlin / gx) * 128;
  int bcol = (nlin % gx) * 128;
  int tid = threadIdx.x;
  int w = tid >> 6, l = tid & 63;
  int wr = (w >> 1) * 64;            // wave row origin in tile
  int wc = (w & 1) * 64;             // wave col origin in tile
  int lrow = l & 15;
  int rslot = ((l >> 4) ^ (lrow >> 2)) * 8;   // swizzled read slot (shorts)
  float4v zero = {0.f, 0.f, 0.f, 0.f};
  float4v acc[4][4];
#pragma unroll
  for (int m = 0; m < 4; ++m)
#pragma unroll
    for (int n = 0; n < 4; ++n) acc[m][n] = zero;

  for (int k0 = 0; k0 < K; k0 += BK) {
#pragma unroll
    for (int it = 0; it < 2; ++it) {
      int idx = tid + it * 256;      // 0..511
      int r = idx >> 2;              // 0..127
      int s = idx & 3;               // 16B slot in k-direction
      int sp = (s ^ ((r >> 2) & 3)) * 8;   // swizzled LDS slot (shorts)
      size_t ao = (size_t)(brow + r) * lda + k0 + s * 8;
      size_t bo = (size_t)(bcol + r) * ldb + k0 + s * 8;
      *(uint4*)&Ash[r][sp] = *(const uint4*)&Ahi[ao];
      *(uint4*)&Asl[r][sp] = *(const uint4*)&Alo[ao];
      *(uint4*)&Bsh[r][sp] = *(const uint4*)&Bhi[bo];
      *(uint4*)&Bsl[r][sp] = *(const uint4*)&Blo[bo];
    }
    __syncthreads();
    short8v ah[4], al[4];
#pragma unroll
    for (int m = 0; m < 4; ++m) {
      int R = wr + m * 16 + lrow;
      ah[m] = *(const short8v*)&Ash[R][rslot];
      al[m] = *(const short8v*)&Asl[R][rslot];
    }
#pragma unroll
    for (int n = 0; n < 4; ++n) {
      int R = wc + n * 16 + lrow;
      short8v bh = *(const short8v*)&Bsh[R][rslot];
      short8v bl = *(const short8v*)&Bsl[R][rslot];
#pragma unroll
      for (int m = 0; m < 4; ++m) {
        acc[m][n] = __builtin_amdgcn_mfma_f32_16x16x32_bf16(ah[m], bh, acc[m][n], 0, 0, 0);
        acc[m][n] = __builtin_amdgcn_mfma_f32_16x16x32_bf16(ah[m], bl, acc[m][n], 0, 0, 0);
        acc[m][n] = __builtin_amdgcn_mfma_f32_16x16x32_bf16(al[m], bh, acc[m][n], 0, 0, 0);
      }
    }
    __syncthreads();
  }
  int drow = (l >> 4) * 4, dcol = l & 15;
#pragma unroll
  for (int m = 0; m < 4; ++m)
#pragma unroll
    for (int n = 0; n < 4; ++n)
#pragma unroll
      for (int j = 0; j < 4; ++j)
        C[(size_t)(brow + wr + m * 16 + drow + j) * N + bcol + wc + n * 16 + dcol] =
            acc[m][n][j];
}

// ---------------------------------------------------------------------------
// C[M x N] = A[M x K] * B[N x K]^T   (row-major, fp32, leading dims lda/ldb)
// Used only for the small dt projection (K=48).
// ---------------------------------------------------------------------------
__global__ __launch_bounds__(256) void gemm_abt(
    const float* __restrict__ A, int lda, const float* __restrict__ B, int ldb,
    float* __restrict__ C, int M, int N, int K) {
  const int BM = 128, BN = 128, BK = 16;
  __shared__ __align__(16) float As[BK][BM + 4];
  __shared__ __align__(16) float Bs[BK][BN + 4];
  int brow = blockIdx.y * BM;
  int bcol = blockIdx.x * BN;
  int tid = threadIdx.x;
  int tr = (tid / 16) * 4;   // 0..60
  int tc = (tid % 16) * 4;   // 0..60
  float acc[2][2][4][4] = {};   // [row-half][col-half][i][j]
  for (int k0 = 0; k0 < K; k0 += BK) {
#pragma unroll
    for (int it = 0; it < 2; ++it) {
      int idx = tid + it * 256;          // 0..511
      int r  = idx >> 2;                 // 0..127
      int cq = (idx & 3) * 4;            // 0,4,8,12
      float4 a = *(const float4*)&A[(size_t)(brow + r) * lda + k0 + cq];
      As[cq + 0][r] = a.x; As[cq + 1][r] = a.y;
      As[cq + 2][r] = a.z; As[cq + 3][r] = a.w;
      float4 b = *(const float4*)&B[(size_t)(bcol + r) * ldb + k0 + cq];
      Bs[cq + 0][r] = b.x; Bs[cq + 1][r] = b.y;
      Bs[cq + 2][r] = b.z; Bs[cq + 3][r] = b.w;
    }
    __syncthreads();
#pragma unroll
    for (int kk = 0; kk < BK; ++kk) {
      float4 a0 = *(const float4*)&As[kk][tr];
      float4 a1 = *(const float4*)&As[kk][tr + 64];
      float4 b0 = *(const float4*)&Bs[kk][tc];
      float4 b1 = *(const float4*)&Bs[kk][tc + 64];
      float ar[2][4] = {{a0.x, a0.y, a0.z, a0.w}, {a1.x, a1.y, a1.z, a1.w}};
      float br[2][4] = {{b0.x, b0.y, b0.z, b0.w}, {b1.x, b1.y, b1.z, b1.w}};
#pragma unroll
      for (int rh = 0; rh < 2; ++rh)
#pragma unroll
        for (int ch = 0; ch < 2; ++ch)
#pragma unroll
          for (int i = 0; i < 4; ++i)
#pragma unroll
            for (int j = 0; j < 4; ++j)
              acc[rh][ch][i][j] += ar[rh][i] * br[ch][j];
    }
    __syncthreads();
  }
#pragma unroll
  for (int rh = 0; rh < 2; ++rh)
#pragma unroll
    for (int i = 0; i < 4; ++i) {
      int row = brow + tr + rh * 64 + i;
#pragma unroll
      for (int ch = 0; ch < 2; ++ch) {
        float4 o = make_float4(acc[rh][ch][i][0], acc[rh][ch][i][1],
                               acc[rh][ch][i][2], acc[rh][ch][i][3]);
        *(float4*)&C[(size_t)row * N + bcol + tc + ch * 64] = o;
      }
    }
}

// ---------------------------------------------------------------------------
// part[slice][M=4096][80] = u[.,kslice] . xp[.,kslice]^T  (split-K, no atomics)
// blockIdx.x: 64-row tile; blockIdx.y: K-slice of 192.  512 blocks total.
// ---------------------------------------------------------------------------
__global__ __launch_bounds__(256) void xproj_gemm(
    const float* __restrict__ u, const float* __restrict__ xp,
    float* __restrict__ part) {
  const int BM = 64, BK = 64;
  __shared__ float As[BK][BM + 1];     // stride 65
  __shared__ float Bs[BK][DBC_W + 1];  // stride 81
  int brow = blockIdx.x * BM;
  int kbase = blockIdx.y * XP_KSL;
  int tid = threadIdx.x;
  int tr = (tid / 16) * 4;    // 0..60
  int tc = (tid % 16) * 5;    // 0..75
  float acc[4][5] = {};
  for (int k0 = kbase; k0 < kbase + XP_KSL; k0 += BK) {
#pragma unroll
    for (int it = 0; it < 4; ++it) {           // A: 64 rows x 64 k
      int lin = tid + it * 256;                // 0..1023
      int r  = lin >> 4;                       // 0..63
      int kq = (lin & 15) * 4;
      float4 a = *(const float4*)&u[(size_t)(brow + r) * D_INNER + k0 + kq];
      As[kq + 0][r] = a.x; As[kq + 1][r] = a.y;
      As[kq + 2][r] = a.z; As[kq + 3][r] = a.w;
    }
#pragma unroll
    for (int it = 0; it < 5; ++it) {           // B: 80 rows x 64 k
      int lin = tid + it * 256;                // 0..1279
      int e  = lin >> 4;                       // 0..79
      int kq = (lin & 15) * 4;
      float4 b = *(const float4*)&xp[(size_t)e * D_INNER + k0 + kq];
      Bs[kq + 0][e] = b.x; Bs[kq + 1][e] = b.y;
      Bs[kq + 2][e] = b.z; Bs[kq + 3][e] = b.w;
    }
    __syncthreads();
#pragma unroll
    for (int kk = 0; kk < BK; ++kk) {
      float ar[4], br[5];
#pragma unroll
      for (int i = 0; i < 4; ++i) ar[i] = As[kk][tr + i];
#pragma unroll
      for (int j = 0; j < 5; ++j) br[j] = Bs[kk][tc + j];
#pragma unroll
      for (int i = 0; i < 4; ++i)
#pragma unroll
        for (int j = 0; j < 5; ++j) acc[i][j] += ar[i] * br[j];
    }
    __syncthreads();
  }
  float* dst = part + (size_t)blockIdx.y * NTOK * DBC_W;
#pragma unroll
  for (int i = 0; i < 4; ++i)
#pragma unroll
    for (int j = 0; j < 5; ++j)
      dst[(size_t)(brow + tr + i) * DBC_W + tc + j] = acc[i][j];
}

// ---------------------------------------------------------------------------
// dbc = sum over XP_KS slices of part.  float4-vectorized.
// ---------------------------------------------------------------------------
__global__ __launch_bounds__(256) void reduce_dbc_kernel(
    const float* __restrict__ part, float* __restrict__ dbc, int n4) {
  int i = blockIdx.x * 256 + threadIdx.x;
  if (i >= n4) return;
  float4 s = ((const float4*)part)[i];
#pragma unroll
  for (int k = 1; k < XP_KS; ++k) {
    float4 v = ((const float4*)(part + (size_t)k * NTOK * DBC_W))[i];
    s.x += v.x; s.y += v.y; s.z += v.z; s.w += v.w;
  }
  ((float4*)dbc)[i] = s;
}

// ---------------------------------------------------------------------------
// Causal depthwise conv (width 4) + bias + SiLU, rolling-window form.
// ---------------------------------------------------------------------------
__global__ __launch_bounds__(256) void conv_silu_kernel(
    const float* __restrict__ xz, const float* __restrict__ cw,
    const float* __restrict__ cb, float* __restrict__ u) {
  int idx = blockIdx.x * 256 + threadIdx.x;
  const int NTC = SEQLEN / CONV_TCH;
  if (idx >= BATCH * NTC * D_INNER) return;
  int c  = idx % D_INNER;
  int tc = (idx / D_INNER) % NTC;
  int b  = idx / (D_INNER * NTC);
  int t0 = tc * CONV_TCH;
  float w0 = cw[c * 4 + 0], w1 = cw[c * 4 + 1];
  float w2 = cw[c * 4 + 2], w3 = cw[c * 4 + 3];
  float bias = cb[c];
  const float* base = xz + (size_t)b * SEQLEN * (2 * D_INNER) + c;
  float xm3 = 0.f, xm2 = 0.f, xm1 = 0.f;
  if (t0 > 0) {
    xm3 = base[(size_t)(t0 - 3) * (2 * D_INNER)];
    xm2 = base[(size_t)(t0 - 2) * (2 * D_INNER)];
    xm1 = base[(size_t)(t0 - 1) * (2 * D_INNER)];
  }
  float* ub = u + (size_t)(b * SEQLEN + t0) * D_INNER + c;
#pragma unroll
  for (int i = 0; i < CONV_TCH; ++i) {
    float xt = base[(size_t)(t0 + i) * (2 * D_INNER)];
    float acc = bias + xm3 * w0 + xm2 * w1 + xm1 * w2 + xt * w3;
    float sig = 1.f / (1.f + __expf(-acc));
    ub[(size_t)i * D_INNER] = acc * sig;
    xm3 = xm2; xm2 = xm1; xm1 = xt;
  }
}

__device__ __forceinline__ float softplusf(float a) {
  return (a > 20.f) ? a : log1pf(__expf(a));
}

// ---------------------------------------------------------------------------
// Blocked selective scan, phase 1.  dty holds RAW dt scores (pre-bias,
// pre-softplus); bias+softplus applied here on the fly.
// ---------------------------------------------------------------------------
__global__ __launch_bounds__(256) void scan_chunk1(
    const float* __restrict__ dty, const float* __restrict__ u,
    const float* __restrict__ dbc, const float* __restrict__ A_log,
    const float* __restrict__ dtb,
    float* __restrict__ S, float* __restrict__ dtsum) {
  int g = blockIdx.x * 256 + threadIdx.x;
  if (g >= BATCH * NC * D_INNER) return;
  int d = g % D_INNER;
  int c = (g / D_INNER) % NC;
  int b = g / (D_INNER * NC);
  float A[D_STATE];
#pragma unroll
  for (int s = 0; s < D_STATE; ++s) A[s] = -__expf(A_log[d * D_STATE + s]);
  float bias = dtb[d];
  float h[D_STATE];
#pragma unroll
  for (int s = 0; s < D_STATE; ++s) h[s] = 0.f;
  float dts = 0.f;
  int t0 = c * CHUNK_T;
  for (int t = t0; t < t0 + CHUNK_T; ++t) {
    size_t rowb = (size_t)b * SEQLEN + t;
    float dtv = softplusf(dty[rowb * D_INNER + d] + bias);
    float uv  = u[rowb * D_INNER + d];
    const float* bc = dbc + rowb * DBC_W;
    float dtu = dtv * uv;
    dts += dtv;
#pragma unroll
    for (int s = 0; s < D_STATE; ++s) {
      float da = __expf(dtv * A[s]);
      h[s] = da * h[s] + dtu * bc[DT_RANK + s];
    }
  }
  size_t base = (((size_t)b * NC + c) * D_STATE) * D_INNER + d;
#pragma unroll
  for (int s = 0; s < D_STATE; ++s) S[base + (size_t)s * D_INNER] = h[s];
  dtsum[((size_t)b * NC + c) * D_INNER + d] = dts;
}

// ---------------------------------------------------------------------------
// Blocked selective scan, phase 2 (serial chunk combine, tiny).
// ---------------------------------------------------------------------------
__global__ __launch_bounds__(256) void scan_combine(
    float* __restrict__ S, const float* __restrict__ dtsum,
    const float* __restrict__ A_log) {
  int g = blockIdx.x * 256 + threadIdx.x;
  if (g >= BATCH * D_INNER) return;
  int b = g / D_INNER, d = g % D_INNER;
  float A[D_STATE];
#pragma unroll
  for (int s = 0; s < D_STATE; ++s) A[s] = -__expf(A_log[d * D_STATE + s]);
  float h[D_STATE];
#pragma unroll
  for (int s = 0; s < D_STATE; ++s) h[s] = 0.f;
  for (int c = 0; c < NC; ++c) {
    size_t base = (((size_t)b * NC + c) * D_STATE) * D_INNER + d;
    float dts = dtsum[((size_t)b * NC + c) * D_INNER + d];
#pragma unroll
    for (int s = 0; s < D_STATE; ++s) {
      size_t off = base + (size_t)s * D_INNER;
      float Sv = S[off];
      S[off] = h[s];                       // h_in for chunk c
      h[s] = __expf(dts * A[s]) * h[s] + Sv;
    }
  }
}

// ---------------------------------------------------------------------------
// Blocked selective scan, phase 3.  Applies bias+softplus to raw dt,
// computes y, D-skip, SiLU(z) gating; writes gated y as split bf16.
// ---------------------------------------------------------------------------
__global__ __launch_bounds__(256) void scan_chunk2(
    const float* __restrict__ dty, const float* __restrict__ u,
    const float* __restrict__ dbc, const float* __restrict__ xz,
    const float* __restrict__ A_log, const float* __restrict__ dtb,
    const float* __restrict__ Dv, const float* __restrict__ hin,
    short* __restrict__ y_hi, short* __restrict__ y_lo) {
  int g = blockIdx.x * 256 + threadIdx.x;
  if (g >= BATCH * NC * D_INNER) return;
  int d = g % D_INNER;
  int c = (g / D_INNER) % NC;
  int b = g / (D_INNER * NC);
  float A[D_STATE];
#pragma unroll
  for (int s = 0; s < D_STATE; ++s) A[s] = -__expf(A_log[d * D_STATE + s]);
  float bias = dtb[d];
  float Dval = Dv[d];
  float h[D_STATE];
  size_t hbase = (((size_t)b * NC + c) * D_STATE) * D_INNER + d;
#pragma unroll
  for (int s = 0; s < D_STATE; ++s) h[s] = hin[hbase + (size_t)s * D_INNER];
  int t0 = c * CHUNK_T;
  for (int t = t0; t < t0 + CHUNK_T; ++t) {
    size_t rowb = (size_t)b * SEQLEN + t;
    float dtv = softplusf(dty[rowb * D_INNER + d] + bias);
    float uv  = u[rowb * D_INNER + d];
    const float* bc = dbc + rowb * DBC_W;
    float dtu = dtv * uv;
    float yv = 0.f;
#pragma unroll
    for (int s = 0; s < D_STATE; ++s) {
      float da = __expf(dtv * A[s]);
      h[s] = da * h[s] + dtu * bc[DT_RANK + s];
      yv += h[s] * bc[DT_RANK + D_STATE + s];
    }
    float zv = xz[rowb * (2 * D_INNER) + D_INNER + d];
    float sig = 1.f / (1.f + __expf(-zv));
    float yo = (yv + uv * Dval) * (zv * sig);
    short hv, lv; split_bf16(yo, hv, lv);
    y_hi[rowb * D_INNER + d] = hv;
    y_lo[rowb * D_INNER + d] = lv;
  }
}

// ---------------------------------------------------------------------------
// Final: residual add + LN(normf) + LN(dec), last rtn tokens only.
// ---------------------------------------------------------------------------
__global__ __launch_bounds__(256) void final_kernel(
    const float* __restrict__ hy, const float* __restrict__ resid,
    const float* __restrict__ fw, const float* __restrict__ fb,
    const float* __restrict__ dw, const float* __restrict__ db,
    float* __restrict__ out, int rtn) {
  int rowo = blockIdx.x;                 // 0 .. BATCH*rtn-1
  int b = rowo / rtn;
  int t = SEQLEN - rtn + (rowo % rtn);
  int tid = threadIdx.x;
  size_t base = ((size_t)b * SEQLEN + t) * D_MODEL;
  __shared__ float red[256];
  __shared__ float s_mu1, s_rs1, s_mu2, s_rs2;
  float v[3];
#pragma unroll
  for (int i = 0; i < 3; ++i) {
    int c = tid + i * 256;
    v[i] = hy[base + c] + resid[base + c];
  }
  // --- LN 1 ---
  red[tid] = v[0] + v[1] + v[2]; __syncthreads();
  for (int off = 128; off > 0; off >>= 1) {
    if (tid < off) red[tid] += red[tid + off];
    __syncthreads();
  }
  if (tid == 0) s_mu1 = red[0] / D_MODEL;
  __syncthreads();
  float mu = s_mu1, q = 0.f;
#pragma unroll
  for (int i = 0; i < 3; ++i) { float dd = v[i] - mu; q += dd * dd; }
  __syncthreads();
  red[tid] = q; __syncthreads();
  for (int off = 128; off > 0; off >>= 1) {
    if (tid < off) red[tid] += red[tid + off];
    __syncthreads();
  }
  if (tid == 0) s_rs1 = rsqrtf(red[0] / D_MODEL + 1e-5f);
  __syncthreads();
  float rs = s_rs1;
#pragma unroll
  for (int i = 0; i < 3; ++i) {
    int c = tid + i * 256;
    v[i] = (v[i] - mu) * rs * fw[c] + fb[c];
  }
  // --- LN 2 ---
  __syncthreads();
  red[tid] = v[0] + v[1] + v[2]; __syncthreads();
  for (int off = 128; off > 0; off >>= 1) {
    if (tid < off) red[tid] += red[tid + off];
    __syncthreads();
  }
  if (tid == 0) s_mu2 = red[0] / D_MODEL;
  __syncthreads();
  mu = s_mu2; q = 0.f;
#pragma unroll
  for (int i = 0; i < 3; ++i) { float dd = v[i] - mu; q += dd * dd; }
  __syncthreads();
  red[tid] = q; __syncthreads();
  for (int off = 128; off > 0; off >>= 1) {
    if (tid < off) red[tid] += red[tid + off];
    __syncthreads();
  }
  if (tid == 0) s_rs2 = rsqrtf(red[0] / D_MODEL + 1e-5f);
  __syncthreads();
  rs = s_rs2;
#pragma unroll
  for (int i = 0; i < 3; ++i) {
    int c = tid + i * 256;
    out[(size_t)rowo * D_MODEL + c] = (v[i] - mu) * rs * dw[c] + db[c];
  }
}

// ---------------------------------------------------------------------------
extern "C" void kernel_launch(void* const* d_in, const int* in_sizes, int n_in,
                              void* d_out, int out_size, void* d_ws, size_t ws_size,
                              hipStream_t stream) {
  const float* x       = (const float*)d_in[0];
  const float* pos     = (const float*)d_in[1];
  const float* norm_w  = (const float*)d_in[2];
  const float* norm_b  = (const float*)d_in[3];
  const float* in_proj = (const float*)d_in[4];
  const float* conv_w  = (const float*)d_in[5];
  const float* conv_b  = (const float*)d_in[6];
  const float* x_proj  = (const float*)d_in[7];
  const float* dt_w    = (const float*)d_in[8];
  const float* dt_b    = (const float*)d_in[9];
  const float* A_log   = (const float*)d_in[10];
  const float* Dv      = (const float*)d_in[11];
  const float* out_proj= (const float*)d_in[12];
  const float* normf_w = (const float*)d_in[13];
  const float* normf_b = (const float*)d_in[14];
  const float* dec_w   = (const float*)d_in[15];
  const float* dec_b   = (const float*)d_in[16];
  int rtn = out_size / (BATCH * D_MODEL);   // return_token_num

  float* ws    = (float*)d_ws;
  float* resid = ws;                                 // NTOK*D_MODEL
  float* hy    = resid + (size_t)NTOK * D_MODEL;     // NTOK*D_MODEL (out_proj out)
  float* xz    = hy    + (size_t)NTOK * D_MODEL;     // NTOK*2*D_INNER
  float* u     = xz    + (size_t)NTOK * 2 * D_INNER; // NTOK*D_INNER
  float* dbc   = u     + (size_t)NTOK * D_INNER;     // NTOK*80
  float* dty   = dbc   + (size_t)NTOK * DBC_W;       // NTOK*D_INNER (raw dt)
  float* Sbuf  = dty   + (size_t)NTOK * D_INNER;     // BATCH*NC*D_STATE*D_INNER
  float* dtsum = Sbuf  + (size_t)BATCH * NC * D_STATE * D_INNER; // BATCH*NC*D_INNER
  float* dbcp  = dtsum + (size_t)BATCH * NC * D_INNER; // XP_KS*NTOK*DBC_W
  short* hh_hi = (short*)(dbcp + (size_t)XP_KS * NTOK * DBC_W);
  short* hh_lo = hh_hi + (size_t)NTOK * D_MODEL;
  short* y_hi  = hh_lo + (size_t)NTOK * D_MODEL;
  short* y_lo  = y_hi  + (size_t)NTOK * D_INNER;
  short* wbh   = y_lo  + (size_t)NTOK * D_INNER;     // 2*D_INNER*D_MODEL shorts
  short* wbl   = wbh   + (size_t)2 * D_INNER * D_MODEL;

  for (int l = 0; l < N_LAYER; ++l) {
    // split in_proj weights for this layer -> wbh/wbl
    split_kernel<<<1024, 256, 0, stream>>>(
        in_proj + (size_t)l * 2 * D_INNER * D_MODEL, wbh, wbl,
        2 * D_INNER * D_MODEL / 4);

    ln_kernel<<<NTOK, 256, 0, stream>>>(x, pos, resid, hy, hh_hi, hh_lo,
        norm_w + l * D_MODEL, norm_b + l * D_MODEL, l == 0);

    dim3 g1(2 * D_INNER / 128, NTOK / 128);
    gemm_bf16x3<<<g1, 256, 0, stream>>>(hh_hi, hh_lo, D_MODEL,
        wbh, wbl, D_MODEL, xz, NTOK, 2 * D_INNER, D_MODEL);

    int convtot = BATCH * (SEQLEN / CONV_TCH) * D_INNER;
    conv_silu_kernel<<<(convtot + 255) / 256, 256, 0, stream>>>(
        xz, conv_w + (size_t)l * D_INNER * D_CONV, conv_b + l * D_INNER, u);

    dim3 gxp(NTOK / 64, XP_KS);
    xproj_gemm<<<gxp, 256, 0, stream>>>(
        u, x_proj + (size_t)l * DBC_W * D_INNER, dbcp);
    reduce_dbc_kernel<<<(NTOK * DBC_W / 4 + 255) / 256, 256, 0, stream>>>(
        dbcp, dbc, NTOK * DBC_W / 4);

    // dt raw scores: dbc[:, :48] @ dt_w^T  -> dty   (M=4096, N=1536, K=48)
    dim3 gdt(D_INNER / 128, NTOK / 128);
    gemm_abt<<<gdt, 256, 0, stream>>>(dbc, DBC_W,
        dt_w + (size_t)l * D_INNER * DT_RANK, DT_RANK, dty,
        NTOK, D_INNER, DT_RANK);

    const float* Al = A_log + (size_t)l * D_INNER * D_STATE;
    const float* dtbl = dt_b + (size_t)l * D_INNER;
    int tot1 = BATCH * NC * D_INNER;
    scan_chunk1<<<(tot1 + 255) / 256, 256, 0, stream>>>(
        dty, u, dbc, Al, dtbl, Sbuf, dtsum);
    scan_combine<<<(BATCH * D_INNER + 255) / 256, 256, 0, stream>>>(
        Sbuf, dtsum, Al);
    scan_chunk2<<<(tot1 + 255) / 256, 256, 0, stream>>>(
        dty, u, dbc, xz, Al, dtbl, Dv + l * D_INNER, Sbuf, y_hi, y_lo);

    // split out_proj weights for this layer -> wbh/wbl (reuse buffer)
    split_kernel<<<1024, 256, 0, stream>>>(
        out_proj + (size_t)l * D_MODEL * D_INNER, wbh, wbl,
        D_MODEL * D_INNER / 4);

    dim3 g2(D_MODEL / 128, NTOK / 128);
    gemm_bf16x3<<<g2, 256, 0, stream>>>(y_hi, y_lo, D_INNER,
        wbh, wbl, D_INNER, hy, NTOK, D_MODEL, D_INNER);
  }

  final_kernel<<<BATCH * rtn, 256, 0, stream>>>(
      hy, resid, normf_w, normf_b, dec_w, dec_b, (float*)d_out, rtn);
}

// Round 9
// 2938.678 us; speedup vs baseline: 1.5936x; 1.0246x over previous
//
#include <hip/hip_runtime.h>
#include <math.h>

#define D_MODEL 768
#define N_LAYER 8
#define D_INNER 1536
#define D_STATE 16
#define DT_RANK 48
#define D_CONV  4
#define BATCH   4
#define SEQLEN  1024
#define NTOK    (BATCH*SEQLEN)      // 4096 token rows
#define DBC_W   (DT_RANK + 2*D_STATE)  // 80
#define NC      32                  // scan chunks per sequence
#define CHUNK_T (SEQLEN/NC)         // 32 timesteps per chunk
#define XP_KS   8                   // xproj split-K slices
#define XP_KSL  (D_INNER/XP_KS)     // 192 k per slice
#define CONV_TCH 16                 // conv outputs per thread

typedef __attribute__((ext_vector_type(8))) short short8v;   // 8 bf16 (4 VGPRs)
typedef __attribute__((ext_vector_type(4))) float float4v;   // 4 fp32 acc

// Split fp32 into hi+lo bf16 (both RNE).  x ~= hi + lo, |err| ~ 2^-17 |x|.
__device__ __forceinline__ void split_bf16(float x, short& hi, short& lo) {
  unsigned u = __float_as_uint(x);
  unsigned r = (u + 0x7fffu + ((u >> 16) & 1u)) >> 16;
  hi = (short)r;
  float fhi = __uint_as_float(r << 16);
  float xl = x - fhi;
  unsigned u2 = __float_as_uint(xl);
  unsigned r2 = (u2 + 0x7fffu + ((u2 >> 16) & 1u)) >> 16;
  lo = (short)r2;
}

// Async global->LDS 16B copy: per-lane global src, wave-uniform LDS base;
// lane i's 16B lands at ldsbase + i*16.
__device__ __forceinline__ void gload16(const short* g, short* l) {
  __builtin_amdgcn_global_load_lds(
      (const __attribute__((address_space(1))) void*)g,
      (__attribute__((address_space(3))) void*)l, 16, 0, 0);
}

// ---------------------------------------------------------------------------
// Weight split: fp32 [n] -> bf16 hi[n], lo[n].  n4 = n/4, float4-vectorized.
// ---------------------------------------------------------------------------
__global__ __launch_bounds__(256) void split_kernel(
    const float* __restrict__ src, short* __restrict__ hi,
    short* __restrict__ lo, int n4) {
  int stride = gridDim.x * 256;
  for (int i = blockIdx.x * 256 + threadIdx.x; i < n4; i += stride) {
    float4 v = ((const float4*)src)[i];
    short4 h, g;
    split_bf16(v.x, h.x, g.x);
    split_bf16(v.y, h.y, g.y);
    split_bf16(v.z, h.z, g.z);
    split_bf16(v.w, h.w, g.w);
    ((short4*)hi)[i] = h;
    ((short4*)lo)[i] = g;
  }
}

// ---------------------------------------------------------------------------
// LayerNorm + residual update.  One block per token row (768 elems, 256 thr).
// ---------------------------------------------------------------------------
__global__ __launch_bounds__(256) void ln_kernel(
    const float* __restrict__ x, const float* __restrict__ pos,
    float* __restrict__ resid, const float* __restrict__ hy,
    short* __restrict__ hh_hi, short* __restrict__ hh_lo,
    const float* __restrict__ w, const float* __restrict__ b, int first) {
  int row = blockIdx.x;
  int tid = threadIdx.x;
  int base = row * D_MODEL;
  __shared__ float red[256];
  __shared__ float s_mu, s_rs;
  float v[3];
#pragma unroll
  for (int i = 0; i < 3; ++i) {
    int c = tid + i * 256;
    float r;
    if (first) r = x[base + c] + pos[base + c];
    else       r = resid[base + c] + hy[base + c];
    resid[base + c] = r;
    v[i] = r;
  }
  float s = v[0] + v[1] + v[2];
  red[tid] = s; __syncthreads();
  for (int off = 128; off > 0; off >>= 1) {
    if (tid < off) red[tid] += red[tid + off];
    __syncthreads();
  }
  if (tid == 0) s_mu = red[0] / D_MODEL;
  __syncthreads();
  float mu = s_mu;
  float q = 0.f;
#pragma unroll
  for (int i = 0; i < 3; ++i) { float d = v[i] - mu; q += d * d; }
  __syncthreads();
  red[tid] = q; __syncthreads();
  for (int off = 128; off > 0; off >>= 1) {
    if (tid < off) red[tid] += red[tid + off];
    __syncthreads();
  }
  if (tid == 0) s_rs = rsqrtf(red[0] / D_MODEL + 1e-5f);
  __syncthreads();
  float rs = s_rs;
#pragma unroll
  for (int i = 0; i < 3; ++i) {
    int c = tid + i * 256;
    float val = (v[i] - mu) * rs * w[c] + b[c];
    short hv, lv; split_bf16(val, hv, lv);
    hh_hi[base + c] = hv;
    hh_lo[base + c] = lv;
  }
}

// ---------------------------------------------------------------------------
// bf16x3 MFMA GEMM:  C[M][N] = A[M][K] . B[N][K]^T  (fp32-equivalent accuracy)
// A,B given as split bf16 (hi,lo).  Computes hi*hi + hi*lo + lo*hi.
// 128x128 tile, BK=32, 256 thr = 4 waves (2x2), 4x4 16x16x32 frags per wave.
// Staging via global_load_lds (width=16): LDS dest is LINEAR [128][32]
// (32 KB total -> 5 blocks/CU); the bank-conflict XOR swizzle is applied on
// the GLOBAL source address (slot s = p ^ ((row>>1)&3)) and mirrored on the
// LDS read side -- both-sides-or-neither (m104/m173 rule).  Read pattern is
// exactly 2-way per 16-lane group (free).  No register staging (round-7
// spill lesson); no XCD swizzle (round-8 FETCH regression: 60->89 MB).
// ---------------------------------------------------------------------------
__global__ __launch_bounds__(256) void gemm_bf16x3(
    const short* __restrict__ Ahi, const short* __restrict__ Alo, int lda,
    const short* __restrict__ Bhi, const short* __restrict__ Blo, int ldb,
    float* __restrict__ C, int M, int N, int K) {
  const int BK = 32;
  __shared__ short Ash[128][32];
  __shared__ short Asl[128][32];
  __shared__ short Bsh[128][32];
  __shared__ short Bsl[128][32];
  int brow = blockIdx.y * 128;
  int bcol = blockIdx.x * 128;
  int tid = threadIdx.x;
  int wv = tid >> 6, l = tid & 63;
  int wr = (wv >> 1) * 64;           // wave row origin in tile
  int wc = (wv & 1) * 64;            // wave col origin in tile
  int lrow = l & 15;
  int rslot = ((l >> 4) ^ ((l >> 1) & 3)) * 8;  // swizzled read slot (shorts)
  int lr = l >> 2;                   // staging: row-within-16 group
  int lp = l & 3;                    // staging: physical 16B slot
  float4v zero = {0.f, 0.f, 0.f, 0.f};
  float4v acc[4][4];
#pragma unroll
  for (int m = 0; m < 4; ++m)
#pragma unroll
    for (int n = 0; n < 4; ++n) acc[m][n] = zero;

  for (int k0 = 0; k0 < K; k0 += BK) {
    // stage 128 rows x 32 k of 4 buffers via async DMA; each wave covers
    // rows [wv*32, wv*32+32) in two 16-row calls per buffer.
#pragma unroll
    for (int half = 0; half < 2; ++half) {
      int row = wv * 32 + half * 16 + lr;          // per-lane source row
      int s = lp ^ ((row >> 1) & 3);               // pre-swizzled k-slot
      int ldsrow = wv * 32 + half * 16;            // wave-uniform LDS base row
      size_t ao = (size_t)(brow + row) * lda + k0 + s * 8;
      size_t bo = (size_t)(bcol + row) * ldb + k0 + s * 8;
      gload16(Ahi + ao, &Ash[ldsrow][0]);
      gload16(Alo + ao, &Asl[ldsrow][0]);
      gload16(Bhi + bo, &Bsh[ldsrow][0]);
      gload16(Blo + bo, &Bsl[ldsrow][0]);
    }
    __syncthreads();
    short8v ah[4], al[4];
#pragma unroll
    for (int m = 0; m < 4; ++m) {
      int R = wr + m * 16 + lrow;
      ah[m] = *(const short8v*)&Ash[R][rslot];
      al[m] = *(const short8v*)&Asl[R][rslot];
    }
#pragma unroll
    for (int n = 0; n < 4; ++n) {
      int R = wc + n * 16 + lrow;
      short8v bh = *(const short8v*)&Bsh[R][rslot];
      short8v bl = *(const short8v*)&Bsl[R][rslot];
#pragma unroll
      for (int m = 0; m < 4; ++m) {
        acc[m][n] = __builtin_amdgcn_mfma_f32_16x16x32_bf16(ah[m], bh, acc[m][n], 0, 0, 0);
        acc[m][n] = __builtin_amdgcn_mfma_f32_16x16x32_bf16(ah[m], bl, acc[m][n], 0, 0, 0);
        acc[m][n] = __builtin_amdgcn_mfma_f32_16x16x32_bf16(al[m], bh, acc[m][n], 0, 0, 0);
      }
    }
    __syncthreads();
  }
  int drow = (l >> 4) * 4, dcol = l & 15;
#pragma unroll
  for (int m = 0; m < 4; ++m)
#pragma unroll
    for (int n = 0; n < 4; ++n)
#pragma unroll
      for (int j = 0; j < 4; ++j)
        C[(size_t)(brow + wr + m * 16 + drow + j) * N + bcol + wc + n * 16 + dcol] =
            acc[m][n][j];
}

// ---------------------------------------------------------------------------
// C[M x N] = A[M x K] * B[N x K]^T   (row-major, fp32, leading dims lda/ldb)
// Used only for the small dt projection (K=48).
// ---------------------------------------------------------------------------
__global__ __launch_bounds__(256) void gemm_abt(
    const float* __restrict__ A, int lda, const float* __restrict__ B, int ldb,
    float* __restrict__ C, int M, int N, int K) {
  const int BM = 128, BN = 128, BK = 16;
  __shared__ __align__(16) float As[BK][BM + 4];
  __shared__ __align__(16) float Bs[BK][BN + 4];
  int brow = blockIdx.y * BM;
  int bcol = blockIdx.x * BN;
  int tid = threadIdx.x;
  int tr = (tid / 16) * 4;   // 0..60
  int tc = (tid % 16) * 4;   // 0..60
  float acc[2][2][4][4] = {};   // [row-half][col-half][i][j]
  for (int k0 = 0; k0 < K; k0 += BK) {
#pragma unroll
    for (int it = 0; it < 2; ++it) {
      int idx = tid + it * 256;          // 0..511
      int r  = idx >> 2;                 // 0..127
      int cq = (idx & 3) * 4;            // 0,4,8,12
      float4 a = *(const float4*)&A[(size_t)(brow + r) * lda + k0 + cq];
      As[cq + 0][r] = a.x; As[cq + 1][r] = a.y;
      As[cq + 2][r] = a.z; As[cq + 3][r] = a.w;
      float4 b = *(const float4*)&B[(size_t)(bcol + r) * ldb + k0 + cq];
      Bs[cq + 0][r] = b.x; Bs[cq + 1][r] = b.y;
      Bs[cq + 2][r] = b.z; Bs[cq + 3][r] = b.w;
    }
    __syncthreads();
#pragma unroll
    for (int kk = 0; kk < BK; ++kk) {
      float4 a0 = *(const float4*)&As[kk][tr];
      float4 a1 = *(const float4*)&As[kk][tr + 64];
      float4 b0 = *(const float4*)&Bs[kk][tc];
      float4 b1 = *(const float4*)&Bs[kk][tc + 64];
      float ar[2][4] = {{a0.x, a0.y, a0.z, a0.w}, {a1.x, a1.y, a1.z, a1.w}};
      float br[2][4] = {{b0.x, b0.y, b0.z, b0.w}, {b1.x, b1.y, b1.z, b1.w}};
#pragma unroll
      for (int rh = 0; rh < 2; ++rh)
#pragma unroll
        for (int ch = 0; ch < 2; ++ch)
#pragma unroll
          for (int i = 0; i < 4; ++i)
#pragma unroll
            for (int j = 0; j < 4; ++j)
              acc[rh][ch][i][j] += ar[rh][i] * br[ch][j];
    }
    __syncthreads();
  }
#pragma unroll
  for (int rh = 0; rh < 2; ++rh)
#pragma unroll
    for (int i = 0; i < 4; ++i) {
      int row = brow + tr + rh * 64 + i;
#pragma unroll
      for (int ch = 0; ch < 2; ++ch) {
        float4 o = make_float4(acc[rh][ch][i][0], acc[rh][ch][i][1],
                               acc[rh][ch][i][2], acc[rh][ch][i][3]);
        *(float4*)&C[(size_t)row * N + bcol + tc + ch * 64] = o;
      }
    }
}

// ---------------------------------------------------------------------------
// part[slice][M=4096][80] = u[.,kslice] . xp[.,kslice]^T  (split-K, no atomics)
// ---------------------------------------------------------------------------
__global__ __launch_bounds__(256) void xproj_gemm(
    const float* __restrict__ u, const float* __restrict__ xp,
    float* __restrict__ part) {
  const int BM = 64, BK = 64;
  __shared__ float As[BK][BM + 1];     // stride 65
  __shared__ float Bs[BK][DBC_W + 1];  // stride 81
  int brow = blockIdx.x * BM;
  int kbase = blockIdx.y * XP_KSL;
  int tid = threadIdx.x;
  int tr = (tid / 16) * 4;    // 0..60
  int tc = (tid % 16) * 5;    // 0..75
  float acc[4][5] = {};
  for (int k0 = kbase; k0 < kbase + XP_KSL; k0 += BK) {
#pragma unroll
    for (int it = 0; it < 4; ++it) {           // A: 64 rows x 64 k
      int lin = tid + it * 256;                // 0..1023
      int r  = lin >> 4;                       // 0..63
      int kq = (lin & 15) * 4;
      float4 a = *(const float4*)&u[(size_t)(brow + r) * D_INNER + k0 + kq];
      As[kq + 0][r] = a.x; As[kq + 1][r] = a.y;
      As[kq + 2][r] = a.z; As[kq + 3][r] = a.w;
    }
#pragma unroll
    for (int it = 0; it < 5; ++it) {           // B: 80 rows x 64 k
      int lin = tid + it * 256;                // 0..1279
      int e  = lin >> 4;                       // 0..79
      int kq = (lin & 15) * 4;
      float4 b = *(const float4*)&xp[(size_t)e * D_INNER + k0 + kq];
      Bs[kq + 0][e] = b.x; Bs[kq + 1][e] = b.y;
      Bs[kq + 2][e] = b.z; Bs[kq + 3][e] = b.w;
    }
    __syncthreads();
#pragma unroll
    for (int kk = 0; kk < BK; ++kk) {
      float ar[4], br[5];
#pragma unroll
      for (int i = 0; i < 4; ++i) ar[i] = As[kk][tr + i];
#pragma unroll
      for (int j = 0; j < 5; ++j) br[j] = Bs[kk][tc + j];
#pragma unroll
      for (int i = 0; i < 4; ++i)
#pragma unroll
        for (int j = 0; j < 5; ++j) acc[i][j] += ar[i] * br[j];
    }
    __syncthreads();
  }
  float* dst = part + (size_t)blockIdx.y * NTOK * DBC_W;
#pragma unroll
  for (int i = 0; i < 4; ++i)
#pragma unroll
    for (int j = 0; j < 5; ++j)
      dst[(size_t)(brow + tr + i) * DBC_W + tc + j] = acc[i][j];
}

// ---------------------------------------------------------------------------
// dbc = sum over XP_KS slices of part.  float4-vectorized.
// ---------------------------------------------------------------------------
__global__ __launch_bounds__(256) void reduce_dbc_kernel(
    const float* __restrict__ part, float* __restrict__ dbc, int n4) {
  int i = blockIdx.x * 256 + threadIdx.x;
  if (i >= n4) return;
  float4 s = ((const float4*)part)[i];
#pragma unroll
  for (int k = 1; k < XP_KS; ++k) {
    float4 v = ((const float4*)(part + (size_t)k * NTOK * DBC_W))[i];
    s.x += v.x; s.y += v.y; s.z += v.z; s.w += v.w;
  }
  ((float4*)dbc)[i] = s;
}

// ---------------------------------------------------------------------------
// Causal depthwise conv (width 4) + bias + SiLU, rolling-window form.
// ---------------------------------------------------------------------------
__global__ __launch_bounds__(256) void conv_silu_kernel(
    const float* __restrict__ xz, const float* __restrict__ cw,
    const float* __restrict__ cb, float* __restrict__ u) {
  int idx = blockIdx.x * 256 + threadIdx.x;
  const int NTC = SEQLEN / CONV_TCH;
  if (idx >= BATCH * NTC * D_INNER) return;
  int c  = idx % D_INNER;
  int tc = (idx / D_INNER) % NTC;
  int b  = idx / (D_INNER * NTC);
  int t0 = tc * CONV_TCH;
  float w0 = cw[c * 4 + 0], w1 = cw[c * 4 + 1];
  float w2 = cw[c * 4 + 2], w3 = cw[c * 4 + 3];
  float bias = cb[c];
  const float* base = xz + (size_t)b * SEQLEN * (2 * D_INNER) + c;
  float xm3 = 0.f, xm2 = 0.f, xm1 = 0.f;
  if (t0 > 0) {
    xm3 = base[(size_t)(t0 - 3) * (2 * D_INNER)];
    xm2 = base[(size_t)(t0 - 2) * (2 * D_INNER)];
    xm1 = base[(size_t)(t0 - 1) * (2 * D_INNER)];
  }
  float* ub = u + (size_t)(b * SEQLEN + t0) * D_INNER + c;
#pragma unroll
  for (int i = 0; i < CONV_TCH; ++i) {
    float xt = base[(size_t)(t0 + i) * (2 * D_INNER)];
    float acc = bias + xm3 * w0 + xm2 * w1 + xm1 * w2 + xt * w3;
    float sig = 1.f / (1.f + __expf(-acc));
    ub[(size_t)i * D_INNER] = acc * sig;
    xm3 = xm2; xm2 = xm1; xm1 = xt;
  }
}

__device__ __forceinline__ float softplusf(float a) {
  return (a > 20.f) ? a : log1pf(__expf(a));
}

// ---------------------------------------------------------------------------
// Blocked selective scan, phase 1.
// ---------------------------------------------------------------------------
__global__ __launch_bounds__(256) void scan_chunk1(
    const float* __restrict__ dty, const float* __restrict__ u,
    const float* __restrict__ dbc, const float* __restrict__ A_log,
    const float* __restrict__ dtb,
    float* __restrict__ S, float* __restrict__ dtsum) {
  int g = blockIdx.x * 256 + threadIdx.x;
  if (g >= BATCH * NC * D_INNER) return;
  int d = g % D_INNER;
  int c = (g / D_INNER) % NC;
  int b = g / (D_INNER * NC);
  float A[D_STATE];
#pragma unroll
  for (int s = 0; s < D_STATE; ++s) A[s] = -__expf(A_log[d * D_STATE + s]);
  float bias = dtb[d];
  float h[D_STATE];
#pragma unroll
  for (int s = 0; s < D_STATE; ++s) h[s] = 0.f;
  float dts = 0.f;
  int t0 = c * CHUNK_T;
  for (int t = t0; t < t0 + CHUNK_T; ++t) {
    size_t rowb = (size_t)b * SEQLEN + t;
    float dtv = softplusf(dty[rowb * D_INNER + d] + bias);
    float uv  = u[rowb * D_INNER + d];
    const float* bc = dbc + rowb * DBC_W;
    float dtu = dtv * uv;
    dts += dtv;
#pragma unroll
    for (int s = 0; s < D_STATE; ++s) {
      float da = __expf(dtv * A[s]);
      h[s] = da * h[s] + dtu * bc[DT_RANK + s];
    }
  }
  size_t base = (((size_t)b * NC + c) * D_STATE) * D_INNER + d;
#pragma unroll
  for (int s = 0; s < D_STATE; ++s) S[base + (size_t)s * D_INNER] = h[s];
  dtsum[((size_t)b * NC + c) * D_INNER + d] = dts;
}

// ---------------------------------------------------------------------------
// Blocked selective scan, phase 2 (serial chunk combine, tiny).
// ---------------------------------------------------------------------------
__global__ __launch_bounds__(256) void scan_combine(
    float* __restrict__ S, const float* __restrict__ dtsum,
    const float* __restrict__ A_log) {
  int g = blockIdx.x * 256 + threadIdx.x;
  if (g >= BATCH * D_INNER) return;
  int b = g / D_INNER, d = g % D_INNER;
  float A[D_STATE];
#pragma unroll
  for (int s = 0; s < D_STATE; ++s) A[s] = -__expf(A_log[d * D_STATE + s]);
  float h[D_STATE];
#pragma unroll
  for (int s = 0; s < D_STATE; ++s) h[s] = 0.f;
  for (int c = 0; c < NC; ++c) {
    size_t base = (((size_t)b * NC + c) * D_STATE) * D_INNER + d;
    float dts = dtsum[((size_t)b * NC + c) * D_INNER + d];
#pragma unroll
    for (int s = 0; s < D_STATE; ++s) {
      size_t off = base + (size_t)s * D_INNER;
      float Sv = S[off];
      S[off] = h[s];                       // h_in for chunk c
      h[s] = __expf(dts * A[s]) * h[s] + Sv;
    }
  }
}

// ---------------------------------------------------------------------------
// Blocked selective scan, phase 3.
// ---------------------------------------------------------------------------
__global__ __launch_bounds__(256) void scan_chunk2(
    const float* __restrict__ dty, const float* __restrict__ u,
    const float* __restrict__ dbc, const float* __restrict__ xz,
    const float* __restrict__ A_log, const float* __restrict__ dtb,
    const float* __restrict__ Dv, const float* __restrict__ hin,
    short* __restrict__ y_hi, short* __restrict__ y_lo) {
  int g = blockIdx.x * 256 + threadIdx.x;
  if (g >= BATCH * NC * D_INNER) return;
  int d = g % D_INNER;
  int c = (g / D_INNER) % NC;
  int b = g / (D_INNER * NC);
  float A[D_STATE];
#pragma unroll
  for (int s = 0; s < D_STATE; ++s) A[s] = -__expf(A_log[d * D_STATE + s]);
  float bias = dtb[d];
  float Dval = Dv[d];
  float h[D_STATE];
  size_t hbase = (((size_t)b * NC + c) * D_STATE) * D_INNER + d;
#pragma unroll
  for (int s = 0; s < D_STATE; ++s) h[s] = hin[hbase + (size_t)s * D_INNER];
  int t0 = c * CHUNK_T;
  for (int t = t0; t < t0 + CHUNK_T; ++t) {
    size_t rowb = (size_t)b * SEQLEN + t;
    float dtv = softplusf(dty[rowb * D_INNER + d] + bias);
    float uv  = u[rowb * D_INNER + d];
    const float* bc = dbc + rowb * DBC_W;
    float dtu = dtv * uv;
    float yv = 0.f;
#pragma unroll
    for (int s = 0; s < D_STATE; ++s) {
      float da = __expf(dtv * A[s]);
      h[s] = da * h[s] + dtu * bc[DT_RANK + s];
      yv += h[s] * bc[DT_RANK + D_STATE + s];
    }
    float zv = xz[rowb * (2 * D_INNER) + D_INNER + d];
    float sig = 1.f / (1.f + __expf(-zv));
    float yo = (yv + uv * Dval) * (zv * sig);
    short hv, lv; split_bf16(yo, hv, lv);
    y_hi[rowb * D_INNER + d] = hv;
    y_lo[rowb * D_INNER + d] = lv;
  }
}

// ---------------------------------------------------------------------------
// Final: residual add + LN(normf) + LN(dec), last rtn tokens only.
// ---------------------------------------------------------------------------
__global__ __launch_bounds__(256) void final_kernel(
    const float* __restrict__ hy, const float* __restrict__ resid,
    const float* __restrict__ fw, const float* __restrict__ fb,
    const float* __restrict__ dw, const float* __restrict__ db,
    float* __restrict__ out, int rtn) {
  int rowo = blockIdx.x;                 // 0 .. BATCH*rtn-1
  int b = rowo / rtn;
  int t = SEQLEN - rtn + (rowo % rtn);
  int tid = threadIdx.x;
  size_t base = ((size_t)b * SEQLEN + t) * D_MODEL;
  __shared__ float red[256];
  __shared__ float s_mu1, s_rs1, s_mu2, s_rs2;
  float v[3];
#pragma unroll
  for (int i = 0; i < 3; ++i) {
    int c = tid + i * 256;
    v[i] = hy[base + c] + resid[base + c];
  }
  // --- LN 1 ---
  red[tid] = v[0] + v[1] + v[2]; __syncthreads();
  for (int off = 128; off > 0; off >>= 1) {
    if (tid < off) red[tid] += red[tid + off];
    __syncthreads();
  }
  if (tid == 0) s_mu1 = red[0] / D_MODEL;
  __syncthreads();
  float mu = s_mu1, q = 0.f;
#pragma unroll
  for (int i = 0; i < 3; ++i) { float dd = v[i] - mu; q += dd * dd; }
  __syncthreads();
  red[tid] = q; __syncthreads();
  for (int off = 128; off > 0; off >>= 1) {
    if (tid < off) red[tid] += red[tid + off];
    __syncthreads();
  }
  if (tid == 0) s_rs1 = rsqrtf(red[0] / D_MODEL + 1e-5f);
  __syncthreads();
  float rs = s_rs1;
#pragma unroll
  for (int i = 0; i < 3; ++i) {
    int c = tid + i * 256;
    v[i] = (v[i] - mu) * rs * fw[c] + fb[c];
  }
  // --- LN 2 ---
  __syncthreads();
  red[tid] = v[0] + v[1] + v[2]; __syncthreads();
  for (int off = 128; off > 0; off >>= 1) {
    if (tid < off) red[tid] += red[tid + off];
    __syncthreads();
  }
  if (tid == 0) s_mu2 = red[0] / D_MODEL;
  __syncthreads();
  mu = s_mu2; q = 0.f;
#pragma unroll
  for (int i = 0; i < 3; ++i) { float dd = v[i] - mu; q += dd * dd; }
  __syncthreads();
  red[tid] = q; __syncthreads();
  for (int off = 128; off > 0; off >>= 1) {
    if (tid < off) red[tid] += red[tid + off];
    __syncthreads();
  }
  if (tid == 0) s_rs2 = rsqrtf(red[0] / D_MODEL + 1e-5f);
  __syncthreads();
  rs = s_rs2;
#pragma unroll
  for (int i = 0; i < 3; ++i) {
    int c = tid + i * 256;
    out[(size_t)rowo * D_MODEL + c] = (v[i] - mu) * rs * dw[c] + db[c];
  }
}

// ---------------------------------------------------------------------------
extern "C" void kernel_launch(void* const* d_in, const int* in_sizes, int n_in,
                              void* d_out, int out_size, void* d_ws, size_t ws_size,
                              hipStream_t stream) {
  const float* x       = (const float*)d_in[0];
  const float* pos     = (const float*)d_in[1];
  const float* norm_w  = (const float*)d_in[2];
  const float* norm_b  = (const float*)d_in[3];
  const float* in_proj = (const float*)d_in[4];
  const float* conv_w  = (const float*)d_in[5];
  const float* conv_b  = (const float*)d_in[6];
  const float* x_proj  = (const float*)d_in[7];
  const float* dt_w    = (const float*)d_in[8];
  const float* dt_b    = (const float*)d_in[9];
  const float* A_log   = (const float*)d_in[10];
  const float* Dv      = (const float*)d_in[11];
  const float* out_proj= (const float*)d_in[12];
  const float* normf_w = (const float*)d_in[13];
  const float* normf_b = (const float*)d_in[14];
  const float* dec_w   = (const float*)d_in[15];
  const float* dec_b   = (const float*)d_in[16];
  int rtn = out_size / (BATCH * D_MODEL);   // return_token_num

  float* ws    = (float*)d_ws;
  float* resid = ws;                                 // NTOK*D_MODEL
  float* hy    = resid + (size_t)NTOK * D_MODEL;     // NTOK*D_MODEL (out_proj out)
  float* xz    = hy    + (size_t)NTOK * D_MODEL;     // NTOK*2*D_INNER
  float* u     = xz    + (size_t)NTOK * 2 * D_INNER; // NTOK*D_INNER
  float* dbc   = u     + (size_t)NTOK * D_INNER;     // NTOK*80
  float* dty   = dbc   + (size_t)NTOK * DBC_W;       // NTOK*D_INNER (raw dt)
  float* Sbuf  = dty   + (size_t)NTOK * D_INNER;     // BATCH*NC*D_STATE*D_INNER
  float* dtsum = Sbuf  + (size_t)BATCH * NC * D_STATE * D_INNER; // BATCH*NC*D_INNER
  float* dbcp  = dtsum + (size_t)BATCH * NC * D_INNER; // XP_KS*NTOK*DBC_W
  short* hh_hi = (short*)(dbcp + (size_t)XP_KS * NTOK * DBC_W);
  short* hh_lo = hh_hi + (size_t)NTOK * D_MODEL;
  short* y_hi  = hh_lo + (size_t)NTOK * D_MODEL;
  short* y_lo  = y_hi  + (size_t)NTOK * D_INNER;
  short* wbh   = y_lo  + (size_t)NTOK * D_INNER;     // 2*D_INNER*D_MODEL shorts
  short* wbl   = wbh   + (size_t)2 * D_INNER * D_MODEL;

  for (int l = 0; l < N_LAYER; ++l) {
    // split in_proj weights for this layer -> wbh/wbl
    split_kernel<<<1024, 256, 0, stream>>>(
        in_proj + (size_t)l * 2 * D_INNER * D_MODEL, wbh, wbl,
        2 * D_INNER * D_MODEL / 4);

    ln_kernel<<<NTOK, 256, 0, stream>>>(x, pos, resid, hy, hh_hi, hh_lo,
        norm_w + l * D_MODEL, norm_b + l * D_MODEL, l == 0);

    dim3 g1(2 * D_INNER / 128, NTOK / 128);
    gemm_bf16x3<<<g1, 256, 0, stream>>>(hh_hi, hh_lo, D_MODEL,
        wbh, wbl, D_MODEL, xz, NTOK, 2 * D_INNER, D_MODEL);

    int convtot = BATCH * (SEQLEN / CONV_TCH) * D_INNER;
    conv_silu_kernel<<<(convtot + 255) / 256, 256, 0, stream>>>(
        xz, conv_w + (size_t)l * D_INNER * D_CONV, conv_b + l * D_INNER, u);

    dim3 gxp(NTOK / 64, XP_KS);
    xproj_gemm<<<gxp, 256, 0, stream>>>(
        u, x_proj + (size_t)l * DBC_W * D_INNER, dbcp);
    reduce_dbc_kernel<<<(NTOK * DBC_W / 4 + 255) / 256, 256, 0, stream>>>(
        dbcp, dbc, NTOK * DBC_W / 4);

    // dt raw scores: dbc[:, :48] @ dt_w^T  -> dty   (M=4096, N=1536, K=48)
    dim3 gdt(D_INNER / 128, NTOK / 128);
    gemm_abt<<<gdt, 256, 0, stream>>>(dbc, DBC_W,
        dt_w + (size_t)l * D_INNER * DT_RANK, DT_RANK, dty,
        NTOK, D_INNER, DT_RANK);

    const float* Al = A_log + (size_t)l * D_INNER * D_STATE;
    const float* dtbl = dt_b + (size_t)l * D_INNER;
    int tot1 = BATCH * NC * D_INNER;
    scan_chunk1<<<(tot1 + 255) / 256, 256, 0, stream>>>(
        dty, u, dbc, Al, dtbl, Sbuf, dtsum);
    scan_combine<<<(BATCH * D_INNER + 255) / 256, 256, 0, stream>>>(
        Sbuf, dtsum, Al);
    scan_chunk2<<<(tot1 + 255) / 256, 256, 0, stream>>>(
        dty, u, dbc, xz, Al, dtbl, Dv + l * D_INNER, Sbuf, y_hi, y_lo);

    // split out_proj weights for this layer -> wbh/wbl (reuse buffer)
    split_kernel<<<1024, 256, 0, stream>>>(
        out_proj + (size_t)l * D_MODEL * D_INNER, wbh, wbl,
        D_MODEL * D_INNER / 4);

    dim3 g2(D_MODEL / 128, NTOK / 128);
    gemm_bf16x3<<<g2, 256, 0, stream>>>(y_hi, y_lo, D_INNER,
        wbh, wbl, D_INNER, hy, NTOK, D_MODEL, D_INNER);
  }

  final_kernel<<<BATCH * rtn, 256, 0, stream>>>(
      hy, resid, normf_w, normf_b, dec_w, dec_b, (float*)d_out, rtn);
}

// Round 10
// 2449.627 us; speedup vs baseline: 1.9118x; 1.1996x over previous
//
#include <hip/hip_runtime.h>
#include <math.h>

#define D_MODEL 768
#define N_LAYER 8
#define D_INNER 1536
#define D_STATE 16
#define DT_RANK 48
#define D_CONV  4
#define BATCH   4
#define SEQLEN  1024
#define NTOK    (BATCH*SEQLEN)      // 4096 token rows
#define DBC_W   (DT_RANK + 2*D_STATE)  // 80
#define NC      64                  // scan chunks per sequence
#define CHUNK_T (SEQLEN/NC)         // 16 timesteps per chunk
#define XP_KS   16                  // xproj split-K slices
#define XP_KSL  (D_INNER/XP_KS)     // 96 k per slice
#define CONV_TCH 16                 // conv outputs per thread

typedef __attribute__((ext_vector_type(8))) short short8v;   // 8 bf16 (4 VGPRs)
typedef __attribute__((ext_vector_type(4))) float float4v;   // 4 fp32 acc

// Split fp32 into hi+lo bf16 (both RNE).  x ~= hi + lo, |err| ~ 2^-17 |x|.
__device__ __forceinline__ void split_bf16(float x, short& hi, short& lo) {
  unsigned u = __float_as_uint(x);
  unsigned r = (u + 0x7fffu + ((u >> 16) & 1u)) >> 16;
  hi = (short)r;
  float fhi = __uint_as_float(r << 16);
  float xl = x - fhi;
  unsigned u2 = __float_as_uint(xl);
  unsigned r2 = (u2 + 0x7fffu + ((u2 >> 16) & 1u)) >> 16;
  lo = (short)r2;
}

// Async global->LDS 16B copy: per-lane global src, wave-uniform LDS base;
// lane i's 16B lands at ldsbase + i*16.
__device__ __forceinline__ void gload16(const short* g, short* l) {
  __builtin_amdgcn_global_load_lds(
      (const __attribute__((address_space(1))) void*)g,
      (__attribute__((address_space(3))) void*)l, 16, 0, 0);
}

// ---------------------------------------------------------------------------
// Weight split: fp32 [n] -> bf16 hi[n], lo[n].  n4 = n/4, float4-vectorized.
// ---------------------------------------------------------------------------
__global__ __launch_bounds__(256) void split_kernel(
    const float* __restrict__ src, short* __restrict__ hi,
    short* __restrict__ lo, int n4) {
  int stride = gridDim.x * 256;
  for (int i = blockIdx.x * 256 + threadIdx.x; i < n4; i += stride) {
    float4 v = ((const float4*)src)[i];
    short4 h, g;
    split_bf16(v.x, h.x, g.x);
    split_bf16(v.y, h.y, g.y);
    split_bf16(v.z, h.z, g.z);
    split_bf16(v.w, h.w, g.w);
    ((short4*)hi)[i] = h;
    ((short4*)lo)[i] = g;
  }
}

// ---------------------------------------------------------------------------
// LayerNorm + residual update.  One block per token row (768 elems, 256 thr).
// ---------------------------------------------------------------------------
__global__ __launch_bounds__(256) void ln_kernel(
    const float* __restrict__ x, const float* __restrict__ pos,
    float* __restrict__ resid, const float* __restrict__ hy,
    short* __restrict__ hh_hi, short* __restrict__ hh_lo,
    const float* __restrict__ w, const float* __restrict__ b, int first) {
  int row = blockIdx.x;
  int tid = threadIdx.x;
  int base = row * D_MODEL;
  __shared__ float red[256];
  __shared__ float s_mu, s_rs;
  float v[3];
#pragma unroll
  for (int i = 0; i < 3; ++i) {
    int c = tid + i * 256;
    float r;
    if (first) r = x[base + c] + pos[base + c];
    else       r = resid[base + c] + hy[base + c];
    resid[base + c] = r;
    v[i] = r;
  }
  float s = v[0] + v[1] + v[2];
  red[tid] = s; __syncthreads();
  for (int off = 128; off > 0; off >>= 1) {
    if (tid < off) red[tid] += red[tid + off];
    __syncthreads();
  }
  if (tid == 0) s_mu = red[0] / D_MODEL;
  __syncthreads();
  float mu = s_mu;
  float q = 0.f;
#pragma unroll
  for (int i = 0; i < 3; ++i) { float d = v[i] - mu; q += d * d; }
  __syncthreads();
  red[tid] = q; __syncthreads();
  for (int off = 128; off > 0; off >>= 1) {
    if (tid < off) red[tid] += red[tid + off];
    __syncthreads();
  }
  if (tid == 0) s_rs = rsqrtf(red[0] / D_MODEL + 1e-5f);
  __syncthreads();
  float rs = s_rs;
#pragma unroll
  for (int i = 0; i < 3; ++i) {
    int c = tid + i * 256;
    float val = (v[i] - mu) * rs * w[c] + b[c];
    short hv, lv; split_bf16(val, hv, lv);
    hh_hi[base + c] = hv;
    hh_lo[base + c] = lv;
  }
}

// ---------------------------------------------------------------------------
// bf16x3 MFMA GEMM:  C[M][N] = A[M][K] . B[N][K]^T  (fp32-equivalent accuracy)
// 128x128 tile, BK=32, 4 waves, global_load_lds staging, source-side XOR
// swizzle mirrored on LDS reads (both-sides rule).  See round-9 notes.
// ---------------------------------------------------------------------------
__global__ __launch_bounds__(256) void gemm_bf16x3(
    const short* __restrict__ Ahi, const short* __restrict__ Alo, int lda,
    const short* __restrict__ Bhi, const short* __restrict__ Blo, int ldb,
    float* __restrict__ C, int M, int N, int K) {
  const int BK = 32;
  __shared__ short Ash[128][32];
  __shared__ short Asl[128][32];
  __shared__ short Bsh[128][32];
  __shared__ short Bsl[128][32];
  int brow = blockIdx.y * 128;
  int bcol = blockIdx.x * 128;
  int tid = threadIdx.x;
  int wv = tid >> 6, l = tid & 63;
  int wr = (wv >> 1) * 64;           // wave row origin in tile
  int wc = (wv & 1) * 64;            // wave col origin in tile
  int lrow = l & 15;
  int rslot = ((l >> 4) ^ ((l >> 1) & 3)) * 8;  // swizzled read slot (shorts)
  int lr = l >> 2;                   // staging: row-within-16 group
  int lp = l & 3;                    // staging: physical 16B slot
  float4v zero = {0.f, 0.f, 0.f, 0.f};
  float4v acc[4][4];
#pragma unroll
  for (int m = 0; m < 4; ++m)
#pragma unroll
    for (int n = 0; n < 4; ++n) acc[m][n] = zero;

  for (int k0 = 0; k0 < K; k0 += BK) {
#pragma unroll
    for (int half = 0; half < 2; ++half) {
      int row = wv * 32 + half * 16 + lr;          // per-lane source row
      int s = lp ^ ((row >> 1) & 3);               // pre-swizzled k-slot
      int ldsrow = wv * 32 + half * 16;            // wave-uniform LDS base row
      size_t ao = (size_t)(brow + row) * lda + k0 + s * 8;
      size_t bo = (size_t)(bcol + row) * ldb + k0 + s * 8;
      gload16(Ahi + ao, &Ash[ldsrow][0]);
      gload16(Alo + ao, &Asl[ldsrow][0]);
      gload16(Bhi + bo, &Bsh[ldsrow][0]);
      gload16(Blo + bo, &Bsl[ldsrow][0]);
    }
    __syncthreads();
    short8v ah[4], al[4];
#pragma unroll
    for (int m = 0; m < 4; ++m) {
      int R = wr + m * 16 + lrow;
      ah[m] = *(const short8v*)&Ash[R][rslot];
      al[m] = *(const short8v*)&Asl[R][rslot];
    }
#pragma unroll
    for (int n = 0; n < 4; ++n) {
      int R = wc + n * 16 + lrow;
      short8v bh = *(const short8v*)&Bsh[R][rslot];
      short8v bl = *(const short8v*)&Bsl[R][rslot];
#pragma unroll
      for (int m = 0; m < 4; ++m) {
        acc[m][n] = __builtin_amdgcn_mfma_f32_16x16x32_bf16(ah[m], bh, acc[m][n], 0, 0, 0);
        acc[m][n] = __builtin_amdgcn_mfma_f32_16x16x32_bf16(ah[m], bl, acc[m][n], 0, 0, 0);
        acc[m][n] = __builtin_amdgcn_mfma_f32_16x16x32_bf16(al[m], bh, acc[m][n], 0, 0, 0);
      }
    }
    __syncthreads();
  }
  int drow = (l >> 4) * 4, dcol = l & 15;
#pragma unroll
  for (int m = 0; m < 4; ++m)
#pragma unroll
    for (int n = 0; n < 4; ++n)
#pragma unroll
      for (int j = 0; j < 4; ++j)
        C[(size_t)(brow + wr + m * 16 + drow + j) * N + bcol + wc + n * 16 + dcol] =
            acc[m][n][j];
}

// ---------------------------------------------------------------------------
// C[M x N] = A[M x K] * B[N x K]^T   (row-major, fp32, leading dims lda/ldb)
// Used only for the small dt projection (K=48).
// ---------------------------------------------------------------------------
__global__ __launch_bounds__(256) void gemm_abt(
    const float* __restrict__ A, int lda, const float* __restrict__ B, int ldb,
    float* __restrict__ C, int M, int N, int K) {
  const int BM = 128, BN = 128, BK = 16;
  __shared__ __align__(16) float As[BK][BM + 4];
  __shared__ __align__(16) float Bs[BK][BN + 4];
  int brow = blockIdx.y * BM;
  int bcol = blockIdx.x * BN;
  int tid = threadIdx.x;
  int tr = (tid / 16) * 4;   // 0..60
  int tc = (tid % 16) * 4;   // 0..60
  float acc[2][2][4][4] = {};   // [row-half][col-half][i][j]
  for (int k0 = 0; k0 < K; k0 += BK) {
#pragma unroll
    for (int it = 0; it < 2; ++it) {
      int idx = tid + it * 256;          // 0..511
      int r  = idx >> 2;                 // 0..127
      int cq = (idx & 3) * 4;            // 0,4,8,12
      float4 a = *(const float4*)&A[(size_t)(brow + r) * lda + k0 + cq];
      As[cq + 0][r] = a.x; As[cq + 1][r] = a.y;
      As[cq + 2][r] = a.z; As[cq + 3][r] = a.w;
      float4 b = *(const float4*)&B[(size_t)(bcol + r) * ldb + k0 + cq];
      Bs[cq + 0][r] = b.x; Bs[cq + 1][r] = b.y;
      Bs[cq + 2][r] = b.z; Bs[cq + 3][r] = b.w;
    }
    __syncthreads();
#pragma unroll
    for (int kk = 0; kk < BK; ++kk) {
      float4 a0 = *(const float4*)&As[kk][tr];
      float4 a1 = *(const float4*)&As[kk][tr + 64];
      float4 b0 = *(const float4*)&Bs[kk][tc];
      float4 b1 = *(const float4*)&Bs[kk][tc + 64];
      float ar[2][4] = {{a0.x, a0.y, a0.z, a0.w}, {a1.x, a1.y, a1.z, a1.w}};
      float br[2][4] = {{b0.x, b0.y, b0.z, b0.w}, {b1.x, b1.y, b1.z, b1.w}};
#pragma unroll
      for (int rh = 0; rh < 2; ++rh)
#pragma unroll
        for (int ch = 0; ch < 2; ++ch)
#pragma unroll
          for (int i = 0; i < 4; ++i)
#pragma unroll
            for (int j = 0; j < 4; ++j)
              acc[rh][ch][i][j] += ar[rh][i] * br[ch][j];
    }
    __syncthreads();
  }
#pragma unroll
  for (int rh = 0; rh < 2; ++rh)
#pragma unroll
    for (int i = 0; i < 4; ++i) {
      int row = brow + tr + rh * 64 + i;
#pragma unroll
      for (int ch = 0; ch < 2; ++ch) {
        float4 o = make_float4(acc[rh][ch][i][0], acc[rh][ch][i][1],
                               acc[rh][ch][i][2], acc[rh][ch][i][3]);
        *(float4*)&C[(size_t)row * N + bcol + tc + ch * 64] = o;
      }
    }
}

// ---------------------------------------------------------------------------
// part[slice][M=4096][80] = u[.,kslice] . xp[.,kslice]^T  (split-K, no atomics)
// blockIdx.x: 64-row tile; blockIdx.y: K-slice of 96.  1024 blocks total.
// BK=32; A-tile stride 68 keeps rows 16B-aligned -> ds_read_b128 A-fragments.
// ---------------------------------------------------------------------------
__global__ __launch_bounds__(256) void xproj_gemm(
    const float* __restrict__ u, const float* __restrict__ xp,
    float* __restrict__ part) {
  const int BM = 64, BK = 32;
  __shared__ __align__(16) float As[BK][BM + 4];   // stride 68 (16B-aligned)
  __shared__ float Bs[BK][DBC_W + 1];              // stride 81
  int brow = blockIdx.x * BM;
  int kbase = blockIdx.y * XP_KSL;
  int tid = threadIdx.x;
  int tr = (tid / 16) * 4;    // 0..60
  int tc = (tid % 16) * 5;    // 0..75
  float acc[4][5] = {};
  for (int k0 = kbase; k0 < kbase + XP_KSL; k0 += BK) {
#pragma unroll
    for (int it = 0; it < 2; ++it) {           // A: 64 rows x 32 k
      int lin = tid + it * 256;                // 0..511
      int r  = lin >> 3;                       // 0..63
      int kq = (lin & 7) * 4;
      float4 a = *(const float4*)&u[(size_t)(brow + r) * D_INNER + k0 + kq];
      As[kq + 0][r] = a.x; As[kq + 1][r] = a.y;
      As[kq + 2][r] = a.z; As[kq + 3][r] = a.w;
    }
#pragma unroll
    for (int it = 0; it < 3; ++it) {           // B: 80 rows x 32 k
      int lin = tid + it * 256;                // 0..767 (need < 640)
      if (lin < 640) {
        int e  = lin >> 3;                     // 0..79
        int kq = (lin & 7) * 4;
        float4 bv = *(const float4*)&xp[(size_t)e * D_INNER + k0 + kq];
        Bs[kq + 0][e] = bv.x; Bs[kq + 1][e] = bv.y;
        Bs[kq + 2][e] = bv.z; Bs[kq + 3][e] = bv.w;
      }
    }
    __syncthreads();
#pragma unroll
    for (int kk = 0; kk < BK; ++kk) {
      float4 av = *(const float4*)&As[kk][tr];
      float ar[4] = {av.x, av.y, av.z, av.w};
      float br[5];
#pragma unroll
      for (int j = 0; j < 5; ++j) br[j] = Bs[kk][tc + j];
#pragma unroll
      for (int i = 0; i < 4; ++i)
#pragma unroll
        for (int j = 0; j < 5; ++j) acc[i][j] += ar[i] * br[j];
    }
    __syncthreads();
  }
  float* dst = part + (size_t)blockIdx.y * NTOK * DBC_W;
#pragma unroll
  for (int i = 0; i < 4; ++i)
#pragma unroll
    for (int j = 0; j < 5; ++j)
      dst[(size_t)(brow + tr + i) * DBC_W + tc + j] = acc[i][j];
}

// ---------------------------------------------------------------------------
// dbc = sum over XP_KS slices of part.  float4-vectorized.
// ---------------------------------------------------------------------------
__global__ __launch_bounds__(256) void reduce_dbc_kernel(
    const float* __restrict__ part, float* __restrict__ dbc, int n4) {
  int i = blockIdx.x * 256 + threadIdx.x;
  if (i >= n4) return;
  float4 s = ((const float4*)part)[i];
#pragma unroll
  for (int k = 1; k < XP_KS; ++k) {
    float4 v = ((const float4*)(part + (size_t)k * NTOK * DBC_W))[i];
    s.x += v.x; s.y += v.y; s.z += v.z; s.w += v.w;
  }
  ((float4*)dbc)[i] = s;
}

// ---------------------------------------------------------------------------
// Causal depthwise conv (width 4) + bias + SiLU, rolling-window form.
// ---------------------------------------------------------------------------
__global__ __launch_bounds__(256) void conv_silu_kernel(
    const float* __restrict__ xz, const float* __restrict__ cw,
    const float* __restrict__ cb, float* __restrict__ u) {
  int idx = blockIdx.x * 256 + threadIdx.x;
  const int NTC = SEQLEN / CONV_TCH;
  if (idx >= BATCH * NTC * D_INNER) return;
  int c  = idx % D_INNER;
  int tc = (idx / D_INNER) % NTC;
  int b  = idx / (D_INNER * NTC);
  int t0 = tc * CONV_TCH;
  float w0 = cw[c * 4 + 0], w1 = cw[c * 4 + 1];
  float w2 = cw[c * 4 + 2], w3 = cw[c * 4 + 3];
  float bias = cb[c];
  const float* base = xz + (size_t)b * SEQLEN * (2 * D_INNER) + c;
  float xm3 = 0.f, xm2 = 0.f, xm1 = 0.f;
  if (t0 > 0) {
    xm3 = base[(size_t)(t0 - 3) * (2 * D_INNER)];
    xm2 = base[(size_t)(t0 - 2) * (2 * D_INNER)];
    xm1 = base[(size_t)(t0 - 1) * (2 * D_INNER)];
  }
  float* ub = u + (size_t)(b * SEQLEN + t0) * D_INNER + c;
#pragma unroll
  for (int i = 0; i < CONV_TCH; ++i) {
    float xt = base[(size_t)(t0 + i) * (2 * D_INNER)];
    float acc = bias + xm3 * w0 + xm2 * w1 + xm1 * w2 + xt * w3;
    float sig = 1.f / (1.f + __expf(-acc));
    ub[(size_t)i * D_INNER] = acc * sig;
    xm3 = xm2; xm2 = xm1; xm1 = xt;
  }
}

__device__ __forceinline__ float softplusf(float a) {
  return (a > 20.f) ? a : log1pf(__expf(a));
}

// ---------------------------------------------------------------------------
// Blocked selective scan, phase 1.  b,c derived from blockIdx ONLY (uniform)
// so the per-timestep dbc row address is wave-uniform -> compiler can emit
// scalar loads instead of 32 per-lane vector loads.  1536 blocks (6/CU).
// ---------------------------------------------------------------------------
__global__ __launch_bounds__(256) void scan_chunk1(
    const float* __restrict__ dty, const float* __restrict__ u,
    const float* __restrict__ dbc, const float* __restrict__ A_log,
    const float* __restrict__ dtb,
    float* __restrict__ S, float* __restrict__ dtsum) {
  int blk = blockIdx.x;                      // 0 .. BATCH*NC*D_INNER/256-1
  int bcq = (blk * 256) / D_INNER;           // uniform: b*NC + c
  int d = blk * 256 - bcq * D_INNER + threadIdx.x;
  int c = bcq & (NC - 1);
  int b = bcq / NC;
  float A[D_STATE];
#pragma unroll
  for (int s = 0; s < D_STATE; ++s) A[s] = -__expf(A_log[d * D_STATE + s]);
  float bias = dtb[d];
  float h[D_STATE];
#pragma unroll
  for (int s = 0; s < D_STATE; ++s) h[s] = 0.f;
  float dts = 0.f;
  int t0 = c * CHUNK_T;
  for (int t = t0; t < t0 + CHUNK_T; ++t) {
    size_t rowb = (size_t)b * SEQLEN + t;    // uniform
    const float* bc = dbc + rowb * DBC_W;    // uniform address -> s_load
    float dtv = softplusf(dty[rowb * D_INNER + d] + bias);
    float uv  = u[rowb * D_INNER + d];
    float dtu = dtv * uv;
    dts += dtv;
#pragma unroll
    for (int s = 0; s < D_STATE; ++s) {
      float da = __expf(dtv * A[s]);
      h[s] = da * h[s] + dtu * bc[DT_RANK + s];
    }
  }
  size_t base = (((size_t)b * NC + c) * D_STATE) * D_INNER + d;
#pragma unroll
  for (int s = 0; s < D_STATE; ++s) S[base + (size_t)s * D_INNER] = h[s];
  dtsum[((size_t)b * NC + c) * D_INNER + d] = dts;
}

// ---------------------------------------------------------------------------
// Blocked selective scan, phase 2 (serial chunk combine).
// One thread per (b, s, d) -- 16x more parallel than per-(b,d).
// ---------------------------------------------------------------------------
__global__ __launch_bounds__(256) void scan_combine(
    float* __restrict__ S, const float* __restrict__ dtsum,
    const float* __restrict__ A_log) {
  int g = blockIdx.x * 256 + threadIdx.x;
  if (g >= BATCH * D_STATE * D_INNER) return;
  int d = g % D_INNER;
  int s = (g / D_INNER) % D_STATE;
  int b = g / (D_INNER * D_STATE);
  float A = -__expf(A_log[d * D_STATE + s]);
  float h = 0.f;
  for (int c = 0; c < NC; ++c) {
    size_t off = (((size_t)b * NC + c) * D_STATE + s) * D_INNER + d;
    float dts = dtsum[((size_t)b * NC + c) * D_INNER + d];
    float Sv = S[off];
    S[off] = h;                          // h_in for chunk c
    h = __expf(dts * A) * h + Sv;
  }
}

// ---------------------------------------------------------------------------
// Blocked selective scan, phase 3.  Same uniform-(b,c) restructure.
// ---------------------------------------------------------------------------
__global__ __launch_bounds__(256) void scan_chunk2(
    const float* __restrict__ dty, const float* __restrict__ u,
    const float* __restrict__ dbc, const float* __restrict__ xz,
    const float* __restrict__ A_log, const float* __restrict__ dtb,
    const float* __restrict__ Dv, const float* __restrict__ hin,
    short* __restrict__ y_hi, short* __restrict__ y_lo) {
  int blk = blockIdx.x;
  int bcq = (blk * 256) / D_INNER;           // uniform: b*NC + c
  int d = blk * 256 - bcq * D_INNER + threadIdx.x;
  int c = bcq & (NC - 1);
  int b = bcq / NC;
  float A[D_STATE];
#pragma unroll
  for (int s = 0; s < D_STATE; ++s) A[s] = -__expf(A_log[d * D_STATE + s]);
  float bias = dtb[d];
  float Dval = Dv[d];
  float h[D_STATE];
  size_t hbase = (((size_t)b * NC + c) * D_STATE) * D_INNER + d;
#pragma unroll
  for (int s = 0; s < D_STATE; ++s) h[s] = hin[hbase + (size_t)s * D_INNER];
  int t0 = c * CHUNK_T;
  for (int t = t0; t < t0 + CHUNK_T; ++t) {
    size_t rowb = (size_t)b * SEQLEN + t;    // uniform
    const float* bc = dbc + rowb * DBC_W;    // uniform address -> s_load
    float dtv = softplusf(dty[rowb * D_INNER + d] + bias);
    float uv  = u[rowb * D_INNER + d];
    float dtu = dtv * uv;
    float yv = 0.f;
#pragma unroll
    for (int s = 0; s < D_STATE; ++s) {
      float da = __expf(dtv * A[s]);
      h[s] = da * h[s] + dtu * bc[DT_RANK + s];
      yv += h[s] * bc[DT_RANK + D_STATE + s];
    }
    float zv = xz[rowb * (2 * D_INNER) + D_INNER + d];
    float sig = 1.f / (1.f + __expf(-zv));
    float yo = (yv + uv * Dval) * (zv * sig);
    short hv, lv; split_bf16(yo, hv, lv);
    y_hi[rowb * D_INNER + d] = hv;
    y_lo[rowb * D_INNER + d] = lv;
  }
}

// ---------------------------------------------------------------------------
// Final: residual add + LN(normf) + LN(dec), last rtn tokens only.
// ---------------------------------------------------------------------------
__global__ __launch_bounds__(256) void final_kernel(
    const float* __restrict__ hy, const float* __restrict__ resid,
    const float* __restrict__ fw, const float* __restrict__ fb,
    const float* __restrict__ dw, const float* __restrict__ db,
    float* __restrict__ out, int rtn) {
  int rowo = blockIdx.x;                 // 0 .. BATCH*rtn-1
  int b = rowo / rtn;
  int t = SEQLEN - rtn + (rowo % rtn);
  int tid = threadIdx.x;
  size_t base = ((size_t)b * SEQLEN + t) * D_MODEL;
  __shared__ float red[256];
  __shared__ float s_mu1, s_rs1, s_mu2, s_rs2;
  float v[3];
#pragma unroll
  for (int i = 0; i < 3; ++i) {
    int c = tid + i * 256;
    v[i] = hy[base + c] + resid[base + c];
  }
  // --- LN 1 ---
  red[tid] = v[0] + v[1] + v[2]; __syncthreads();
  for (int off = 128; off > 0; off >>= 1) {
    if (tid < off) red[tid] += red[tid + off];
    __syncthreads();
  }
  if (tid == 0) s_mu1 = red[0] / D_MODEL;
  __syncthreads();
  float mu = s_mu1, q = 0.f;
#pragma unroll
  for (int i = 0; i < 3; ++i) { float dd = v[i] - mu; q += dd * dd; }
  __syncthreads();
  red[tid] = q; __syncthreads();
  for (int off = 128; off > 0; off >>= 1) {
    if (tid < off) red[tid] += red[tid + off];
    __syncthreads();
  }
  if (tid == 0) s_rs1 = rsqrtf(red[0] / D_MODEL + 1e-5f);
  __syncthreads();
  float rs = s_rs1;
#pragma unroll
  for (int i = 0; i < 3; ++i) {
    int c = tid + i * 256;
    v[i] = (v[i] - mu) * rs * fw[c] + fb[c];
  }
  // --- LN 2 ---
  __syncthreads();
  red[tid] = v[0] + v[1] + v[2]; __syncthreads();
  for (int off = 128; off > 0; off >>= 1) {
    if (tid < off) red[tid] += red[tid + off];
    __syncthreads();
  }
  if (tid == 0) s_mu2 = red[0] / D_MODEL;
  __syncthreads();
  mu = s_mu2; q = 0.f;
#pragma unroll
  for (int i = 0; i < 3; ++i) { float dd = v[i] - mu; q += dd * dd; }
  __syncthreads();
  red[tid] = q; __syncthreads();
  for (int off = 128; off > 0; off >>= 1) {
    if (tid < off) red[tid] += red[tid + off];
    __syncthreads();
  }
  if (tid == 0) s_rs2 = rsqrtf(red[0] / D_MODEL + 1e-5f);
  __syncthreads();
  rs = s_rs2;
#pragma unroll
  for (int i = 0; i < 3; ++i) {
    int c = tid + i * 256;
    out[(size_t)rowo * D_MODEL + c] = (v[i] - mu) * rs * dw[c] + db[c];
  }
}

// ---------------------------------------------------------------------------
extern "C" void kernel_launch(void* const* d_in, const int* in_sizes, int n_in,
                              void* d_out, int out_size, void* d_ws, size_t ws_size,
                              hipStream_t stream) {
  const float* x       = (const float*)d_in[0];
  const float* pos     = (const float*)d_in[1];
  const float* norm_w  = (const float*)d_in[2];
  const float* norm_b  = (const float*)d_in[3];
  const float* in_proj = (const float*)d_in[4];
  const float* conv_w  = (const float*)d_in[5];
  const float* conv_b  = (const float*)d_in[6];
  const float* x_proj  = (const float*)d_in[7];
  const float* dt_w    = (const float*)d_in[8];
  const float* dt_b    = (const float*)d_in[9];
  const float* A_log   = (const float*)d_in[10];
  const float* Dv      = (const float*)d_in[11];
  const float* out_proj= (const float*)d_in[12];
  const float* normf_w = (const float*)d_in[13];
  const float* normf_b = (const float*)d_in[14];
  const float* dec_w   = (const float*)d_in[15];
  const float* dec_b   = (const float*)d_in[16];
  int rtn = out_size / (BATCH * D_MODEL);   // return_token_num

  float* ws    = (float*)d_ws;
  float* resid = ws;                                 // NTOK*D_MODEL
  float* hy    = resid + (size_t)NTOK * D_MODEL;     // NTOK*D_MODEL (out_proj out)
  float* xz    = hy    + (size_t)NTOK * D_MODEL;     // NTOK*2*D_INNER
  float* u     = xz    + (size_t)NTOK * 2 * D_INNER; // NTOK*D_INNER
  float* dbc   = u     + (size_t)NTOK * D_INNER;     // NTOK*80
  float* dty   = dbc   + (size_t)NTOK * DBC_W;       // NTOK*D_INNER (raw dt)
  float* Sbuf  = dty   + (size_t)NTOK * D_INNER;     // BATCH*NC*D_STATE*D_INNER
  float* dtsum = Sbuf  + (size_t)BATCH * NC * D_STATE * D_INNER; // BATCH*NC*D_INNER
  float* dbcp  = dtsum + (size_t)BATCH * NC * D_INNER; // XP_KS*NTOK*DBC_W
  short* hh_hi = (short*)(dbcp + (size_t)XP_KS * NTOK * DBC_W);
  short* hh_lo = hh_hi + (size_t)NTOK * D_MODEL;
  short* y_hi  = hh_lo + (size_t)NTOK * D_MODEL;
  short* y_lo  = y_hi  + (size_t)NTOK * D_INNER;
  short* wbh   = y_lo  + (size_t)NTOK * D_INNER;     // 2*D_INNER*D_MODEL shorts
  short* wbl   = wbh   + (size_t)2 * D_INNER * D_MODEL;

  for (int l = 0; l < N_LAYER; ++l) {
    // split in_proj weights for this layer -> wbh/wbl
    split_kernel<<<1024, 256, 0, stream>>>(
        in_proj + (size_t)l * 2 * D_INNER * D_MODEL, wbh, wbl,
        2 * D_INNER * D_MODEL / 4);

    ln_kernel<<<NTOK, 256, 0, stream>>>(x, pos, resid, hy, hh_hi, hh_lo,
        norm_w + l * D_MODEL, norm_b + l * D_MODEL, l == 0);

    dim3 g1(2 * D_INNER / 128, NTOK / 128);
    gemm_bf16x3<<<g1, 256, 0, stream>>>(hh_hi, hh_lo, D_MODEL,
        wbh, wbl, D_MODEL, xz, NTOK, 2 * D_INNER, D_MODEL);

    int convtot = BATCH * (SEQLEN / CONV_TCH) * D_INNER;
    conv_silu_kernel<<<(convtot + 255) / 256, 256, 0, stream>>>(
        xz, conv_w + (size_t)l * D_INNER * D_CONV, conv_b + l * D_INNER, u);

    dim3 gxp(NTOK / 64, XP_KS);
    xproj_gemm<<<gxp, 256, 0, stream>>>(
        u, x_proj + (size_t)l * DBC_W * D_INNER, dbcp);
    reduce_dbc_kernel<<<(NTOK * DBC_W / 4 + 255) / 256, 256, 0, stream>>>(
        dbcp, dbc, NTOK * DBC_W / 4);

    // dt raw scores: dbc[:, :48] @ dt_w^T  -> dty   (M=4096, N=1536, K=48)
    dim3 gdt(D_INNER / 128, NTOK / 128);
    gemm_abt<<<gdt, 256, 0, stream>>>(dbc, DBC_W,
        dt_w + (size_t)l * D_INNER * DT_RANK, DT_RANK, dty,
        NTOK, D_INNER, DT_RANK);

    const float* Al = A_log + (size_t)l * D_INNER * D_STATE;
    const float* dtbl = dt_b + (size_t)l * D_INNER;
    int tot1 = BATCH * NC * D_INNER;
    scan_chunk1<<<tot1 / 256, 256, 0, stream>>>(
        dty, u, dbc, Al, dtbl, Sbuf, dtsum);
    scan_combine<<<(BATCH * D_STATE * D_INNER + 255) / 256, 256, 0, stream>>>(
        Sbuf, dtsum, Al);
    scan_chunk2<<<tot1 / 256, 256, 0, stream>>>(
        dty, u, dbc, xz, Al, dtbl, Dv + l * D_INNER, Sbuf, y_hi, y_lo);

    // split out_proj weights for this layer -> wbh/wbl (reuse buffer)
    split_kernel<<<1024, 256, 0, stream>>>(
        out_proj + (size_t)l * D_MODEL * D_INNER, wbh, wbl,
        D_MODEL * D_INNER / 4);

    dim3 g2(D_MODEL / 128, NTOK / 128);
    gemm_bf16x3<<<g2, 256, 0, stream>>>(y_hi, y_lo, D_INNER,
        wbh, wbl, D_INNER, hy, NTOK, D_MODEL, D_INNER);
  }

  final_kernel<<<BATCH * rtn, 256, 0, stream>>>(
      hy, resid, normf_w, normf_b, dec_w, dec_b, (float*)d_out, rtn);
}

// Round 11
// 2364.756 us; speedup vs baseline: 1.9804x; 1.0359x over previous
//
#include <hip/hip_runtime.h>
#include <math.h>

#define D_MODEL 768
#define N_LAYER 8
#define D_INNER 1536
#define D_STATE 16
#define DT_RANK 48
#define D_CONV  4
#define BATCH   4
#define SEQLEN  1024
#define NTOK    (BATCH*SEQLEN)      // 4096 token rows
#define DBC_W   (DT_RANK + 2*D_STATE)  // 80
#define NC      64                  // scan chunks per sequence
#define CHUNK_T (SEQLEN/NC)         // 16 timesteps per chunk
#define XP_KS   16                  // xproj split-K slices
#define XP_KSL  (D_INNER/XP_KS)     // 96 k per slice
#define CONV_TCH 16                 // conv outputs per thread
#define OP_KS   4                   // out_proj split-K slices

typedef __attribute__((ext_vector_type(8))) short short8v;   // 8 bf16 (4 VGPRs)
typedef __attribute__((ext_vector_type(4))) float float4v;   // 4 fp32 acc

// Split fp32 into hi+lo bf16 (both RNE).  x ~= hi + lo, |err| ~ 2^-17 |x|.
__device__ __forceinline__ void split_bf16(float x, short& hi, short& lo) {
  unsigned u = __float_as_uint(x);
  unsigned r = (u + 0x7fffu + ((u >> 16) & 1u)) >> 16;
  hi = (short)r;
  float fhi = __uint_as_float(r << 16);
  float xl = x - fhi;
  unsigned u2 = __float_as_uint(xl);
  unsigned r2 = (u2 + 0x7fffu + ((u2 >> 16) & 1u)) >> 16;
  lo = (short)r2;
}

// Async global->LDS 16B copy: per-lane global src, wave-uniform LDS base;
// lane i's 16B lands at ldsbase + i*16.
__device__ __forceinline__ void gload16(const short* g, short* l) {
  __builtin_amdgcn_global_load_lds(
      (const __attribute__((address_space(1))) void*)g,
      (__attribute__((address_space(3))) void*)l, 16, 0, 0);
}

// ---------------------------------------------------------------------------
// Weight split: fp32 [n] -> bf16 hi[n], lo[n].  n4 = n/4, float4-vectorized.
// ---------------------------------------------------------------------------
__global__ __launch_bounds__(256) void split_kernel(
    const float* __restrict__ src, short* __restrict__ hi,
    short* __restrict__ lo, int n4) {
  int stride = gridDim.x * 256;
  for (int i = blockIdx.x * 256 + threadIdx.x; i < n4; i += stride) {
    float4 v = ((const float4*)src)[i];
    short4 h, g;
    split_bf16(v.x, h.x, g.x);
    split_bf16(v.y, h.y, g.y);
    split_bf16(v.z, h.z, g.z);
    split_bf16(v.w, h.w, g.w);
    ((short4*)hi)[i] = h;
    ((short4*)lo)[i] = g;
  }
}

// ---------------------------------------------------------------------------
// LayerNorm + residual update.  One block per token row (768 elems, 256 thr).
// ---------------------------------------------------------------------------
__global__ __launch_bounds__(256) void ln_kernel(
    const float* __restrict__ x, const float* __restrict__ pos,
    float* __restrict__ resid, const float* __restrict__ hy,
    short* __restrict__ hh_hi, short* __restrict__ hh_lo,
    const float* __restrict__ w, const float* __restrict__ b, int first) {
  int row = blockIdx.x;
  int tid = threadIdx.x;
  int base = row * D_MODEL;
  __shared__ float red[256];
  __shared__ float s_mu, s_rs;
  float v[3];
#pragma unroll
  for (int i = 0; i < 3; ++i) {
    int c = tid + i * 256;
    float r;
    if (first) r = x[base + c] + pos[base + c];
    else       r = resid[base + c] + hy[base + c];
    resid[base + c] = r;
    v[i] = r;
  }
  float s = v[0] + v[1] + v[2];
  red[tid] = s; __syncthreads();
  for (int off = 128; off > 0; off >>= 1) {
    if (tid < off) red[tid] += red[tid + off];
    __syncthreads();
  }
  if (tid == 0) s_mu = red[0] / D_MODEL;
  __syncthreads();
  float mu = s_mu;
  float q = 0.f;
#pragma unroll
  for (int i = 0; i < 3; ++i) { float d = v[i] - mu; q += d * d; }
  __syncthreads();
  red[tid] = q; __syncthreads();
  for (int off = 128; off > 0; off >>= 1) {
    if (tid < off) red[tid] += red[tid + off];
    __syncthreads();
  }
  if (tid == 0) s_rs = rsqrtf(red[0] / D_MODEL + 1e-5f);
  __syncthreads();
  float rs = s_rs;
#pragma unroll
  for (int i = 0; i < 3; ++i) {
    int c = tid + i * 256;
    float val = (v[i] - mu) * rs * w[c] + b[c];
    short hv, lv; split_bf16(val, hv, lv);
    hh_hi[base + c] = hv;
    hh_lo[base + c] = lv;
  }
}

// ---------------------------------------------------------------------------
// bf16x3 MFMA GEMM:  C[M][N] = A[M][K] . B[N][K]^T  (fp32-equivalent accuracy)
// 128x128 tile, BK=32, 4 waves, global_load_lds staging, source-side XOR
// swizzle mirrored on LDS reads (both-sides rule).
// Split-K: blockIdx.z selects a K-slice of K/gridDim.z; slice z writes its
// partial tile to C + z*M*N (deterministic, no atomics -- round-5 lesson).
// For gridDim.z==1 this is the plain GEMM.
// ---------------------------------------------------------------------------
__global__ __launch_bounds__(256) void gemm_bf16x3(
    const short* __restrict__ Ahi, const short* __restrict__ Alo, int lda,
    const short* __restrict__ Bhi, const short* __restrict__ Blo, int ldb,
    float* __restrict__ C, int M, int N, int K) {
  const int BK = 32;
  __shared__ short Ash[128][32];
  __shared__ short Asl[128][32];
  __shared__ short Bsh[128][32];
  __shared__ short Bsl[128][32];
  int brow = blockIdx.y * 128;
  int bcol = blockIdx.x * 128;
  int ksl = K / gridDim.z;
  int kbeg = blockIdx.z * ksl;
  int kend = kbeg + ksl;
  float* Cw = C + (size_t)blockIdx.z * M * N;
  int tid = threadIdx.x;
  int wv = tid >> 6, l = tid & 63;
  int wr = (wv >> 1) * 64;           // wave row origin in tile
  int wc = (wv & 1) * 64;            // wave col origin in tile
  int lrow = l & 15;
  int rslot = ((l >> 4) ^ ((l >> 1) & 3)) * 8;  // swizzled read slot (shorts)
  int lr = l >> 2;                   // staging: row-within-16 group
  int lp = l & 3;                    // staging: physical 16B slot
  float4v zero = {0.f, 0.f, 0.f, 0.f};
  float4v acc[4][4];
#pragma unroll
  for (int m = 0; m < 4; ++m)
#pragma unroll
    for (int n = 0; n < 4; ++n) acc[m][n] = zero;

  for (int k0 = kbeg; k0 < kend; k0 += BK) {
#pragma unroll
    for (int half = 0; half < 2; ++half) {
      int row = wv * 32 + half * 16 + lr;          // per-lane source row
      int s = lp ^ ((row >> 1) & 3);               // pre-swizzled k-slot
      int ldsrow = wv * 32 + half * 16;            // wave-uniform LDS base row
      size_t ao = (size_t)(brow + row) * lda + k0 + s * 8;
      size_t bo = (size_t)(bcol + row) * ldb + k0 + s * 8;
      gload16(Ahi + ao, &Ash[ldsrow][0]);
      gload16(Alo + ao, &Asl[ldsrow][0]);
      gload16(Bhi + bo, &Bsh[ldsrow][0]);
      gload16(Blo + bo, &Bsl[ldsrow][0]);
    }
    __syncthreads();
    short8v ah[4], al[4];
#pragma unroll
    for (int m = 0; m < 4; ++m) {
      int R = wr + m * 16 + lrow;
      ah[m] = *(const short8v*)&Ash[R][rslot];
      al[m] = *(const short8v*)&Asl[R][rslot];
    }
#pragma unroll
    for (int n = 0; n < 4; ++n) {
      int R = wc + n * 16 + lrow;
      short8v bh = *(const short8v*)&Bsh[R][rslot];
      short8v bl = *(const short8v*)&Bsl[R][rslot];
#pragma unroll
      for (int m = 0; m < 4; ++m) {
        acc[m][n] = __builtin_amdgcn_mfma_f32_16x16x32_bf16(ah[m], bh, acc[m][n], 0, 0, 0);
        acc[m][n] = __builtin_amdgcn_mfma_f32_16x16x32_bf16(ah[m], bl, acc[m][n], 0, 0, 0);
        acc[m][n] = __builtin_amdgcn_mfma_f32_16x16x32_bf16(al[m], bh, acc[m][n], 0, 0, 0);
      }
    }
    __syncthreads();
  }
  int drow = (l >> 4) * 4, dcol = l & 15;
#pragma unroll
  for (int m = 0; m < 4; ++m)
#pragma unroll
    for (int n = 0; n < 4; ++n)
#pragma unroll
      for (int j = 0; j < 4; ++j)
        Cw[(size_t)(brow + wr + m * 16 + drow + j) * N + bcol + wc + n * 16 + dcol] =
            acc[m][n][j];
}

// ---------------------------------------------------------------------------
// out = sum over OP_KS slices of part (float4-vectorized).
// ---------------------------------------------------------------------------
__global__ __launch_bounds__(256) void reduce_out_kernel(
    const float* __restrict__ part, float* __restrict__ out, int n4) {
  int i = blockIdx.x * 256 + threadIdx.x;
  if (i >= n4) return;
  float4 s = ((const float4*)part)[i];
#pragma unroll
  for (int k = 1; k < OP_KS; ++k) {
    float4 v = ((const float4*)(part + (size_t)k * NTOK * D_MODEL))[i];
    s.x += v.x; s.y += v.y; s.z += v.z; s.w += v.w;
  }
  ((float4*)out)[i] = s;
}

// ---------------------------------------------------------------------------
// C[M x N] = A[M x K] * B[N x K]^T   (row-major, fp32, leading dims lda/ldb)
// Used only for the small dt projection (K=48).
// ---------------------------------------------------------------------------
__global__ __launch_bounds__(256) void gemm_abt(
    const float* __restrict__ A, int lda, const float* __restrict__ B, int ldb,
    float* __restrict__ C, int M, int N, int K) {
  const int BM = 128, BN = 128, BK = 16;
  __shared__ __align__(16) float As[BK][BM + 4];
  __shared__ __align__(16) float Bs[BK][BN + 4];
  int brow = blockIdx.y * BM;
  int bcol = blockIdx.x * BN;
  int tid = threadIdx.x;
  int tr = (tid / 16) * 4;   // 0..60
  int tc = (tid % 16) * 4;   // 0..60
  float acc[2][2][4][4] = {};   // [row-half][col-half][i][j]
  for (int k0 = 0; k0 < K; k0 += BK) {
#pragma unroll
    for (int it = 0; it < 2; ++it) {
      int idx = tid + it * 256;          // 0..511
      int r  = idx >> 2;                 // 0..127
      int cq = (idx & 3) * 4;            // 0,4,8,12
      float4 a = *(const float4*)&A[(size_t)(brow + r) * lda + k0 + cq];
      As[cq + 0][r] = a.x; As[cq + 1][r] = a.y;
      As[cq + 2][r] = a.z; As[cq + 3][r] = a.w;
      float4 b = *(const float4*)&B[(size_t)(bcol + r) * ldb + k0 + cq];
      Bs[cq + 0][r] = b.x; Bs[cq + 1][r] = b.y;
      Bs[cq + 2][r] = b.z; Bs[cq + 3][r] = b.w;
    }
    __syncthreads();
#pragma unroll
    for (int kk = 0; kk < BK; ++kk) {
      float4 a0 = *(const float4*)&As[kk][tr];
      float4 a1 = *(const float4*)&As[kk][tr + 64];
      float4 b0 = *(const float4*)&Bs[kk][tc];
      float4 b1 = *(const float4*)&Bs[kk][tc + 64];
      float ar[2][4] = {{a0.x, a0.y, a0.z, a0.w}, {a1.x, a1.y, a1.z, a1.w}};
      float br[2][4] = {{b0.x, b0.y, b0.z, b0.w}, {b1.x, b1.y, b1.z, b1.w}};
#pragma unroll
      for (int rh = 0; rh < 2; ++rh)
#pragma unroll
        for (int ch = 0; ch < 2; ++ch)
#pragma unroll
          for (int i = 0; i < 4; ++i)
#pragma unroll
            for (int j = 0; j < 4; ++j)
              acc[rh][ch][i][j] += ar[rh][i] * br[ch][j];
    }
    __syncthreads();
  }
#pragma unroll
  for (int rh = 0; rh < 2; ++rh)
#pragma unroll
    for (int i = 0; i < 4; ++i) {
      int row = brow + tr + rh * 64 + i;
#pragma unroll
      for (int ch = 0; ch < 2; ++ch) {
        float4 o = make_float4(acc[rh][ch][i][0], acc[rh][ch][i][1],
                               acc[rh][ch][i][2], acc[rh][ch][i][3]);
        *(float4*)&C[(size_t)row * N + bcol + tc + ch * 64] = o;
      }
    }
}

// ---------------------------------------------------------------------------
// part[slice][M=4096][80] = u[.,kslice] . xp[.,kslice]^T  (split-K, no atomics)
// blockIdx.x: 64-row tile; blockIdx.y: K-slice of 96.  1024 blocks total.
// ---------------------------------------------------------------------------
__global__ __launch_bounds__(256) void xproj_gemm(
    const float* __restrict__ u, const float* __restrict__ xp,
    float* __restrict__ part) {
  const int BM = 64, BK = 32;
  __shared__ __align__(16) float As[BK][BM + 4];   // stride 68 (16B-aligned)
  __shared__ float Bs[BK][DBC_W + 1];              // stride 81
  int brow = blockIdx.x * BM;
  int kbase = blockIdx.y * XP_KSL;
  int tid = threadIdx.x;
  int tr = (tid / 16) * 4;    // 0..60
  int tc = (tid % 16) * 5;    // 0..75
  float acc[4][5] = {};
  for (int k0 = kbase; k0 < kbase + XP_KSL; k0 += BK) {
#pragma unroll
    for (int it = 0; it < 2; ++it) {           // A: 64 rows x 32 k
      int lin = tid + it * 256;                // 0..511
      int r  = lin >> 3;                       // 0..63
      int kq = (lin & 7) * 4;
      float4 a = *(const float4*)&u[(size_t)(brow + r) * D_INNER + k0 + kq];
      As[kq + 0][r] = a.x; As[kq + 1][r] = a.y;
      As[kq + 2][r] = a.z; As[kq + 3][r] = a.w;
    }
#pragma unroll
    for (int it = 0; it < 3; ++it) {           // B: 80 rows x 32 k
      int lin = tid + it * 256;                // 0..767 (need < 640)
      if (lin < 640) {
        int e  = lin >> 3;                     // 0..79
        int kq = (lin & 7) * 4;
        float4 bv = *(const float4*)&xp[(size_t)e * D_INNER + k0 + kq];
        Bs[kq + 0][e] = bv.x; Bs[kq + 1][e] = bv.y;
        Bs[kq + 2][e] = bv.z; Bs[kq + 3][e] = bv.w;
      }
    }
    __syncthreads();
#pragma unroll
    for (int kk = 0; kk < BK; ++kk) {
      float4 av = *(const float4*)&As[kk][tr];
      float ar[4] = {av.x, av.y, av.z, av.w};
      float br[5];
#pragma unroll
      for (int j = 0; j < 5; ++j) br[j] = Bs[kk][tc + j];
#pragma unroll
      for (int i = 0; i < 4; ++i)
#pragma unroll
        for (int j = 0; j < 5; ++j) acc[i][j] += ar[i] * br[j];
    }
    __syncthreads();
  }
  float* dst = part + (size_t)blockIdx.y * NTOK * DBC_W;
#pragma unroll
  for (int i = 0; i < 4; ++i)
#pragma unroll
    for (int j = 0; j < 5; ++j)
      dst[(size_t)(brow + tr + i) * DBC_W + tc + j] = acc[i][j];
}

// ---------------------------------------------------------------------------
// dbc = sum over XP_KS slices of part.  float4-vectorized.
// ---------------------------------------------------------------------------
__global__ __launch_bounds__(256) void reduce_dbc_kernel(
    const float* __restrict__ part, float* __restrict__ dbc, int n4) {
  int i = blockIdx.x * 256 + threadIdx.x;
  if (i >= n4) return;
  float4 s = ((const float4*)part)[i];
#pragma unroll
  for (int k = 1; k < XP_KS; ++k) {
    float4 v = ((const float4*)(part + (size_t)k * NTOK * DBC_W))[i];
    s.x += v.x; s.y += v.y; s.z += v.z; s.w += v.w;
  }
  ((float4*)dbc)[i] = s;
}

// ---------------------------------------------------------------------------
// Causal depthwise conv (width 4) + bias + SiLU, rolling-window form.
// ---------------------------------------------------------------------------
__global__ __launch_bounds__(256) void conv_silu_kernel(
    const float* __restrict__ xz, const float* __restrict__ cw,
    const float* __restrict__ cb, float* __restrict__ u) {
  int idx = blockIdx.x * 256 + threadIdx.x;
  const int NTC = SEQLEN / CONV_TCH;
  if (idx >= BATCH * NTC * D_INNER) return;
  int c  = idx % D_INNER;
  int tc = (idx / D_INNER) % NTC;
  int b  = idx / (D_INNER * NTC);
  int t0 = tc * CONV_TCH;
  float w0 = cw[c * 4 + 0], w1 = cw[c * 4 + 1];
  float w2 = cw[c * 4 + 2], w3 = cw[c * 4 + 3];
  float bias = cb[c];
  const float* base = xz + (size_t)b * SEQLEN * (2 * D_INNER) + c;
  float xm3 = 0.f, xm2 = 0.f, xm1 = 0.f;
  if (t0 > 0) {
    xm3 = base[(size_t)(t0 - 3) * (2 * D_INNER)];
    xm2 = base[(size_t)(t0 - 2) * (2 * D_INNER)];
    xm1 = base[(size_t)(t0 - 1) * (2 * D_INNER)];
  }
  float* ub = u + (size_t)(b * SEQLEN + t0) * D_INNER + c;
#pragma unroll
  for (int i = 0; i < CONV_TCH; ++i) {
    float xt = base[(size_t)(t0 + i) * (2 * D_INNER)];
    float acc = bias + xm3 * w0 + xm2 * w1 + xm1 * w2 + xt * w3;
    float sig = 1.f / (1.f + __expf(-acc));
    ub[(size_t)i * D_INNER] = acc * sig;
    xm3 = xm2; xm2 = xm1; xm1 = xt;
  }
}

__device__ __forceinline__ float softplusf(float a) {
  return (a > 20.f) ? a : log1pf(__expf(a));
}

// ---------------------------------------------------------------------------
// Blocked selective scan, phase 1.  b,c derived from blockIdx ONLY (uniform)
// so the per-timestep dbc row address is wave-uniform -> scalar loads.
// ---------------------------------------------------------------------------
__global__ __launch_bounds__(256) void scan_chunk1(
    const float* __restrict__ dty, const float* __restrict__ u,
    const float* __restrict__ dbc, const float* __restrict__ A_log,
    const float* __restrict__ dtb,
    float* __restrict__ S, float* __restrict__ dtsum) {
  int blk = blockIdx.x;                      // 0 .. BATCH*NC*D_INNER/256-1
  int bcq = (blk * 256) / D_INNER;           // uniform: b*NC + c
  int d = blk * 256 - bcq * D_INNER + threadIdx.x;
  int c = bcq & (NC - 1);
  int b = bcq / NC;
  float A[D_STATE];
#pragma unroll
  for (int s = 0; s < D_STATE; ++s) A[s] = -__expf(A_log[d * D_STATE + s]);
  float bias = dtb[d];
  float h[D_STATE];
#pragma unroll
  for (int s = 0; s < D_STATE; ++s) h[s] = 0.f;
  float dts = 0.f;
  int t0 = c * CHUNK_T;
  for (int t = t0; t < t0 + CHUNK_T; ++t) {
    size_t rowb = (size_t)b * SEQLEN + t;    // uniform
    const float* bc = dbc + rowb * DBC_W;    // uniform address -> s_load
    float dtv = softplusf(dty[rowb * D_INNER + d] + bias);
    float uv  = u[rowb * D_INNER + d];
    float dtu = dtv * uv;
    dts += dtv;
#pragma unroll
    for (int s = 0; s < D_STATE; ++s) {
      float da = __expf(dtv * A[s]);
      h[s] = da * h[s] + dtu * bc[DT_RANK + s];
    }
  }
  size_t base = (((size_t)b * NC + c) * D_STATE) * D_INNER + d;
#pragma unroll
  for (int s = 0; s < D_STATE; ++s) S[base + (size_t)s * D_INNER] = h[s];
  dtsum[((size_t)b * NC + c) * D_INNER + d] = dts;
}

// ---------------------------------------------------------------------------
// Blocked selective scan, phase 2 (serial chunk combine).
// One thread per (b, s, d).
// ---------------------------------------------------------------------------
__global__ __launch_bounds__(256) void scan_combine(
    float* __restrict__ S, const float* __restrict__ dtsum,
    const float* __restrict__ A_log) {
  int g = blockIdx.x * 256 + threadIdx.x;
  if (g >= BATCH * D_STATE * D_INNER) return;
  int d = g % D_INNER;
  int s = (g / D_INNER) % D_STATE;
  int b = g / (D_INNER * D_STATE);
  float A = -__expf(A_log[d * D_STATE + s]);
  float h = 0.f;
  for (int c = 0; c < NC; ++c) {
    size_t off = (((size_t)b * NC + c) * D_STATE + s) * D_INNER + d;
    float dts = dtsum[((size_t)b * NC + c) * D_INNER + d];
    float Sv = S[off];
    S[off] = h;                          // h_in for chunk c
    h = __expf(dts * A) * h + Sv;
  }
}

// ---------------------------------------------------------------------------
// Blocked selective scan, phase 3.  Same uniform-(b,c) restructure.
// ---------------------------------------------------------------------------
__global__ __launch_bounds__(256) void scan_chunk2(
    const float* __restrict__ dty, const float* __restrict__ u,
    const float* __restrict__ dbc, const float* __restrict__ xz,
    const float* __restrict__ A_log, const float* __restrict__ dtb,
    const float* __restrict__ Dv, const float* __restrict__ hin,
    short* __restrict__ y_hi, short* __restrict__ y_lo) {
  int blk = blockIdx.x;
  int bcq = (blk * 256) / D_INNER;           // uniform: b*NC + c
  int d = blk * 256 - bcq * D_INNER + threadIdx.x;
  int c = bcq & (NC - 1);
  int b = bcq / NC;
  float A[D_STATE];
#pragma unroll
  for (int s = 0; s < D_STATE; ++s) A[s] = -__expf(A_log[d * D_STATE + s]);
  float bias = dtb[d];
  float Dval = Dv[d];
  float h[D_STATE];
  size_t hbase = (((size_t)b * NC + c) * D_STATE) * D_INNER + d;
#pragma unroll
  for (int s = 0; s < D_STATE; ++s) h[s] = hin[hbase + (size_t)s * D_INNER];
  int t0 = c * CHUNK_T;
  for (int t = t0; t < t0 + CHUNK_T; ++t) {
    size_t rowb = (size_t)b * SEQLEN + t;    // uniform
    const float* bc = dbc + rowb * DBC_W;    // uniform address -> s_load
    float dtv = softplusf(dty[rowb * D_INNER + d] + bias);
    float uv  = u[rowb * D_INNER + d];
    float dtu = dtv * uv;
    float yv = 0.f;
#pragma unroll
    for (int s = 0; s < D_STATE; ++s) {
      float da = __expf(dtv * A[s]);
      h[s] = da * h[s] + dtu * bc[DT_RANK + s];
      yv += h[s] * bc[DT_RANK + D_STATE + s];
    }
    float zv = xz[rowb * (2 * D_INNER) + D_INNER + d];
    float sig = 1.f / (1.f + __expf(-zv));
    float yo = (yv + uv * Dval) * (zv * sig);
    short hv, lv; split_bf16(yo, hv, lv);
    y_hi[rowb * D_INNER + d] = hv;
    y_lo[rowb * D_INNER + d] = lv;
  }
}

// ---------------------------------------------------------------------------
// Final: residual add + LN(normf) + LN(dec), last rtn tokens only.
// ---------------------------------------------------------------------------
__global__ __launch_bounds__(256) void final_kernel(
    const float* __restrict__ hy, const float* __restrict__ resid,
    const float* __restrict__ fw, const float* __restrict__ fb,
    const float* __restrict__ dw, const float* __restrict__ db,
    float* __restrict__ out, int rtn) {
  int rowo = blockIdx.x;                 // 0 .. BATCH*rtn-1
  int b = rowo / rtn;
  int t = SEQLEN - rtn + (rowo % rtn);
  int tid = threadIdx.x;
  size_t base = ((size_t)b * SEQLEN + t) * D_MODEL;
  __shared__ float red[256];
  __shared__ float s_mu1, s_rs1, s_mu2, s_rs2;
  float v[3];
#pragma unroll
  for (int i = 0; i < 3; ++i) {
    int c = tid + i * 256;
    v[i] = hy[base + c] + resid[base + c];
  }
  // --- LN 1 ---
  red[tid] = v[0] + v[1] + v[2]; __syncthreads();
  for (int off = 128; off > 0; off >>= 1) {
    if (tid < off) red[tid] += red[tid + off];
    __syncthreads();
  }
  if (tid == 0) s_mu1 = red[0] / D_MODEL;
  __syncthreads();
  float mu = s_mu1, q = 0.f;
#pragma unroll
  for (int i = 0; i < 3; ++i) { float dd = v[i] - mu; q += dd * dd; }
  __syncthreads();
  red[tid] = q; __syncthreads();
  for (int off = 128; off > 0; off >>= 1) {
    if (tid < off) red[tid] += red[tid + off];
    __syncthreads();
  }
  if (tid == 0) s_rs1 = rsqrtf(red[0] / D_MODEL + 1e-5f);
  __syncthreads();
  float rs = s_rs1;
#pragma unroll
  for (int i = 0; i < 3; ++i) {
    int c = tid + i * 256;
    v[i] = (v[i] - mu) * rs * fw[c] + fb[c];
  }
  // --- LN 2 ---
  __syncthreads();
  red[tid] = v[0] + v[1] + v[2]; __syncthreads();
  for (int off = 128; off > 0; off >>= 1) {
    if (tid < off) red[tid] += red[tid + off];
    __syncthreads();
  }
  if (tid == 0) s_mu2 = red[0] / D_MODEL;
  __syncthreads();
  mu = s_mu2; q = 0.f;
#pragma unroll
  for (int i = 0; i < 3; ++i) { float dd = v[i] - mu; q += dd * dd; }
  __syncthreads();
  red[tid] = q; __syncthreads();
  for (int off = 128; off > 0; off >>= 1) {
    if (tid < off) red[tid] += red[tid + off];
    __syncthreads();
  }
  if (tid == 0) s_rs2 = rsqrtf(red[0] / D_MODEL + 1e-5f);
  __syncthreads();
  rs = s_rs2;
#pragma unroll
  for (int i = 0; i < 3; ++i) {
    int c = tid + i * 256;
    out[(size_t)rowo * D_MODEL + c] = (v[i] - mu) * rs * dw[c] + db[c];
  }
}

// ---------------------------------------------------------------------------
extern "C" void kernel_launch(void* const* d_in, const int* in_sizes, int n_in,
                              void* d_out, int out_size, void* d_ws, size_t ws_size,
                              hipStream_t stream) {
  const float* x       = (const float*)d_in[0];
  const float* pos     = (const float*)d_in[1];
  const float* norm_w  = (const float*)d_in[2];
  const float* norm_b  = (const float*)d_in[3];
  const float* in_proj = (const float*)d_in[4];
  const float* conv_w  = (const float*)d_in[5];
  const float* conv_b  = (const float*)d_in[6];
  const float* x_proj  = (const float*)d_in[7];
  const float* dt_w    = (const float*)d_in[8];
  const float* dt_b    = (const float*)d_in[9];
  const float* A_log   = (const float*)d_in[10];
  const float* Dv      = (const float*)d_in[11];
  const float* out_proj= (const float*)d_in[12];
  const float* normf_w = (const float*)d_in[13];
  const float* normf_b = (const float*)d_in[14];
  const float* dec_w   = (const float*)d_in[15];
  const float* dec_b   = (const float*)d_in[16];
  int rtn = out_size / (BATCH * D_MODEL);   // return_token_num

  float* ws    = (float*)d_ws;
  float* resid = ws;                                 // NTOK*D_MODEL
  float* hy    = resid + (size_t)NTOK * D_MODEL;     // NTOK*D_MODEL (out_proj out)
  float* xz    = hy    + (size_t)NTOK * D_MODEL;     // NTOK*2*D_INNER
  float* u     = xz    + (size_t)NTOK * 2 * D_INNER; // NTOK*D_INNER
  float* dbc   = u     + (size_t)NTOK * D_INNER;     // NTOK*80
  float* dty   = dbc   + (size_t)NTOK * DBC_W;       // NTOK*D_INNER (raw dt)
  float* Sbuf  = dty   + (size_t)NTOK * D_INNER;     // BATCH*NC*D_STATE*D_INNER
  float* dtsum = Sbuf  + (size_t)BATCH * NC * D_STATE * D_INNER; // BATCH*NC*D_INNER
  float* dbcp  = dtsum + (size_t)BATCH * NC * D_INNER; // XP_KS*NTOK*DBC_W
  short* hh_hi = (short*)(dbcp + (size_t)XP_KS * NTOK * DBC_W);
  short* hh_lo = hh_hi + (size_t)NTOK * D_MODEL;
  short* y_hi  = hh_lo + (size_t)NTOK * D_MODEL;
  short* y_lo  = y_hi  + (size_t)NTOK * D_INNER;
  short* wbh   = y_lo  + (size_t)NTOK * D_INNER;     // 2*D_INNER*D_MODEL shorts
  short* wbl   = wbh   + (size_t)2 * D_INNER * D_MODEL;
  // out_proj split-K partials reuse xz (z consumed by scan_chunk2 by then);
  // OP_KS * NTOK*D_MODEL floats = 50.3 MB == sizeof(xz).
  float* opart = xz;

  for (int l = 0; l < N_LAYER; ++l) {
    // split in_proj weights for this layer -> wbh/wbl
    split_kernel<<<1024, 256, 0, stream>>>(
        in_proj + (size_t)l * 2 * D_INNER * D_MODEL, wbh, wbl,
        2 * D_INNER * D_MODEL / 4);

    ln_kernel<<<NTOK, 256, 0, stream>>>(x, pos, resid, hy, hh_hi, hh_lo,
        norm_w + l * D_MODEL, norm_b + l * D_MODEL, l == 0);

    dim3 g1(2 * D_INNER / 128, NTOK / 128, 1);
    gemm_bf16x3<<<g1, 256, 0, stream>>>(hh_hi, hh_lo, D_MODEL,
        wbh, wbl, D_MODEL, xz, NTOK, 2 * D_INNER, D_MODEL);

    int convtot = BATCH * (SEQLEN / CONV_TCH) * D_INNER;
    conv_silu_kernel<<<(convtot + 255) / 256, 256, 0, stream>>>(
        xz, conv_w + (size_t)l * D_INNER * D_CONV, conv_b + l * D_INNER, u);

    dim3 gxp(NTOK / 64, XP_KS);
    xproj_gemm<<<gxp, 256, 0, stream>>>(
        u, x_proj + (size_t)l * DBC_W * D_INNER, dbcp);
    reduce_dbc_kernel<<<(NTOK * DBC_W / 4 + 255) / 256, 256, 0, stream>>>(
        dbcp, dbc, NTOK * DBC_W / 4);

    // dt raw scores: dbc[:, :48] @ dt_w^T  -> dty   (M=4096, N=1536, K=48)
    dim3 gdt(D_INNER / 128, NTOK / 128);
    gemm_abt<<<gdt, 256, 0, stream>>>(dbc, DBC_W,
        dt_w + (size_t)l * D_INNER * DT_RANK, DT_RANK, dty,
        NTOK, D_INNER, DT_RANK);

    const float* Al = A_log + (size_t)l * D_INNER * D_STATE;
    const float* dtbl = dt_b + (size_t)l * D_INNER;
    int tot1 = BATCH * NC * D_INNER;
    scan_chunk1<<<tot1 / 256, 256, 0, stream>>>(
        dty, u, dbc, Al, dtbl, Sbuf, dtsum);
    scan_combine<<<(BATCH * D_STATE * D_INNER + 255) / 256, 256, 0, stream>>>(
        Sbuf, dtsum, Al);
    scan_chunk2<<<tot1 / 256, 256, 0, stream>>>(
        dty, u, dbc, xz, Al, dtbl, Dv + l * D_INNER, Sbuf, y_hi, y_lo);

    // split out_proj weights for this layer -> wbh/wbl (reuse buffer)
    split_kernel<<<1024, 256, 0, stream>>>(
        out_proj + (size_t)l * D_MODEL * D_INNER, wbh, wbl,
        D_MODEL * D_INNER / 4);

    // out_proj split-K=4: partials into opart (reused xz), then reduce -> hy
    dim3 g2(D_MODEL / 128, NTOK / 128, OP_KS);
    gemm_bf16x3<<<g2, 256, 0, stream>>>(y_hi, y_lo, D_INNER,
        wbh, wbl, D_INNER, opart, NTOK, D_MODEL, D_INNER);
    reduce_out_kernel<<<(NTOK * D_MODEL / 4 + 255) / 256, 256, 0, stream>>>(
        opart, hy, NTOK * D_MODEL / 4);
  }

  final_kernel<<<BATCH * rtn, 256, 0, stream>>>(
      hy, resid, normf_w, normf_b, dec_w, dec_b, (float*)d_out, rtn);
}

// Round 12
// 2138.787 us; speedup vs baseline: 2.1896x; 1.1057x over previous
//
#include <hip/hip_runtime.h>
#include <math.h>

#define D_MODEL 768
#define N_LAYER 8
#define D_INNER 1536
#define D_STATE 16
#define DT_RANK 48
#define D_CONV  4
#define BATCH   4
#define SEQLEN  1024
#define NTOK    (BATCH*SEQLEN)      // 4096 token rows
#define DBC_W   (DT_RANK + 2*D_STATE)  // 80
#define NC      64                  // scan chunks per sequence
#define CHUNK_T (SEQLEN/NC)         // 16 timesteps per chunk
#define XP_KS   16                  // xproj split-K slices
#define XP_KSL  (D_INNER/XP_KS)     // 96 k per slice
#define CONV_TCH 16                 // conv outputs per thread
#define OP_KS   4                   // out_proj split-K slices

typedef __attribute__((ext_vector_type(8))) short short8v;   // 8 bf16 (4 VGPRs)
typedef __attribute__((ext_vector_type(4))) float float4v;   // 4 fp32 acc

// Split fp32 into hi+lo bf16 (both RNE).  x ~= hi + lo, |err| ~ 2^-17 |x|.
__device__ __forceinline__ void split_bf16(float x, short& hi, short& lo) {
  unsigned u = __float_as_uint(x);
  unsigned r = (u + 0x7fffu + ((u >> 16) & 1u)) >> 16;
  hi = (short)r;
  float fhi = __uint_as_float(r << 16);
  float xl = x - fhi;
  unsigned u2 = __float_as_uint(xl);
  unsigned r2 = (u2 + 0x7fffu + ((u2 >> 16) & 1u)) >> 16;
  lo = (short)r2;
}

// Async global->LDS 16B copy: per-lane global src, wave-uniform LDS base;
// lane i's 16B lands at ldsbase + i*16.
__device__ __forceinline__ void gload16(const short* g, short* l) {
  __builtin_amdgcn_global_load_lds(
      (const __attribute__((address_space(1))) void*)g,
      (__attribute__((address_space(3))) void*)l, 16, 0, 0);
}

// ---------------------------------------------------------------------------
// Weight split: fp32 [n] -> bf16 hi[n], lo[n].  n4 = n/4, float4-vectorized.
// Called ONCE per launch for all layers' weights (hoisted out of layer loop).
// ---------------------------------------------------------------------------
__global__ __launch_bounds__(256) void split_kernel(
    const float* __restrict__ src, short* __restrict__ hi,
    short* __restrict__ lo, int n4) {
  int stride = gridDim.x * 256;
  for (int i = blockIdx.x * 256 + threadIdx.x; i < n4; i += stride) {
    float4 v = ((const float4*)src)[i];
    short4 h, g;
    split_bf16(v.x, h.x, g.x);
    split_bf16(v.y, h.y, g.y);
    split_bf16(v.z, h.z, g.z);
    split_bf16(v.w, h.w, g.w);
    ((short4*)hi)[i] = h;
    ((short4*)lo)[i] = g;
  }
}

// ---------------------------------------------------------------------------
// LayerNorm + residual update, with out_proj split-K reduction FUSED.
// first=1: r = x + pos.  first=0: r = resid + sum_k opart[k] (prev out_proj).
// Writes r to resid; writes normalized output as split bf16 (hh_hi/hh_lo).
// ---------------------------------------------------------------------------
__global__ __launch_bounds__(256) void ln_kernel(
    const float* __restrict__ x, const float* __restrict__ pos,
    float* __restrict__ resid, const float* __restrict__ opart,
    short* __restrict__ hh_hi, short* __restrict__ hh_lo,
    const float* __restrict__ w, const float* __restrict__ b, int first) {
  int row = blockIdx.x;
  int tid = threadIdx.x;
  int base = row * D_MODEL;
  __shared__ float red[256];
  __shared__ float s_mu, s_rs;
  float v[3];
#pragma unroll
  for (int i = 0; i < 3; ++i) {
    int c = tid + i * 256;
    float r;
    if (first) {
      r = x[base + c] + pos[base + c];
    } else {
      float hysum = opart[base + c];
#pragma unroll
      for (int k = 1; k < OP_KS; ++k)
        hysum += opart[(size_t)k * NTOK * D_MODEL + base + c];
      r = resid[base + c] + hysum;
    }
    resid[base + c] = r;
    v[i] = r;
  }
  float s = v[0] + v[1] + v[2];
  red[tid] = s; __syncthreads();
  for (int off = 128; off > 0; off >>= 1) {
    if (tid < off) red[tid] += red[tid + off];
    __syncthreads();
  }
  if (tid == 0) s_mu = red[0] / D_MODEL;
  __syncthreads();
  float mu = s_mu;
  float q = 0.f;
#pragma unroll
  for (int i = 0; i < 3; ++i) { float d = v[i] - mu; q += d * d; }
  __syncthreads();
  red[tid] = q; __syncthreads();
  for (int off = 128; off > 0; off >>= 1) {
    if (tid < off) red[tid] += red[tid + off];
    __syncthreads();
  }
  if (tid == 0) s_rs = rsqrtf(red[0] / D_MODEL + 1e-5f);
  __syncthreads();
  float rs = s_rs;
#pragma unroll
  for (int i = 0; i < 3; ++i) {
    int c = tid + i * 256;
    float val = (v[i] - mu) * rs * w[c] + b[c];
    short hv, lv; split_bf16(val, hv, lv);
    hh_hi[base + c] = hv;
    hh_lo[base + c] = lv;
  }
}

// ---------------------------------------------------------------------------
// bf16x3 MFMA GEMM:  C[M][N] = A[M][K] . B[N][K]^T  (fp32-equivalent accuracy)
// 128x128 tile, BK=32, 4 waves, global_load_lds staging, source-side XOR
// swizzle mirrored on LDS reads (both-sides rule).
// Split-K: blockIdx.z selects a K-slice; slice z writes partials to C+z*M*N.
// ---------------------------------------------------------------------------
__global__ __launch_bounds__(256) void gemm_bf16x3(
    const short* __restrict__ Ahi, const short* __restrict__ Alo, int lda,
    const short* __restrict__ Bhi, const short* __restrict__ Blo, int ldb,
    float* __restrict__ C, int M, int N, int K) {
  const int BK = 32;
  __shared__ short Ash[128][32];
  __shared__ short Asl[128][32];
  __shared__ short Bsh[128][32];
  __shared__ short Bsl[128][32];
  int brow = blockIdx.y * 128;
  int bcol = blockIdx.x * 128;
  int ksl = K / gridDim.z;
  int kbeg = blockIdx.z * ksl;
  int kend = kbeg + ksl;
  float* Cw = C + (size_t)blockIdx.z * M * N;
  int tid = threadIdx.x;
  int wv = tid >> 6, l = tid & 63;
  int wr = (wv >> 1) * 64;           // wave row origin in tile
  int wc = (wv & 1) * 64;            // wave col origin in tile
  int lrow = l & 15;
  int rslot = ((l >> 4) ^ ((l >> 1) & 3)) * 8;  // swizzled read slot (shorts)
  int lr = l >> 2;                   // staging: row-within-16 group
  int lp = l & 3;                    // staging: physical 16B slot
  float4v zero = {0.f, 0.f, 0.f, 0.f};
  float4v acc[4][4];
#pragma unroll
  for (int m = 0; m < 4; ++m)
#pragma unroll
    for (int n = 0; n < 4; ++n) acc[m][n] = zero;

  for (int k0 = kbeg; k0 < kend; k0 += BK) {
#pragma unroll
    for (int half = 0; half < 2; ++half) {
      int row = wv * 32 + half * 16 + lr;          // per-lane source row
      int s = lp ^ ((row >> 1) & 3);               // pre-swizzled k-slot
      int ldsrow = wv * 32 + half * 16;            // wave-uniform LDS base row
      size_t ao = (size_t)(brow + row) * lda + k0 + s * 8;
      size_t bo = (size_t)(bcol + row) * ldb + k0 + s * 8;
      gload16(Ahi + ao, &Ash[ldsrow][0]);
      gload16(Alo + ao, &Asl[ldsrow][0]);
      gload16(Bhi + bo, &Bsh[ldsrow][0]);
      gload16(Blo + bo, &Bsl[ldsrow][0]);
    }
    __syncthreads();
    short8v ah[4], al[4];
#pragma unroll
    for (int m = 0; m < 4; ++m) {
      int R = wr + m * 16 + lrow;
      ah[m] = *(const short8v*)&Ash[R][rslot];
      al[m] = *(const short8v*)&Asl[R][rslot];
    }
#pragma unroll
    for (int n = 0; n < 4; ++n) {
      int R = wc + n * 16 + lrow;
      short8v bh = *(const short8v*)&Bsh[R][rslot];
      short8v bl = *(const short8v*)&Bsl[R][rslot];
#pragma unroll
      for (int m = 0; m < 4; ++m) {
        acc[m][n] = __builtin_amdgcn_mfma_f32_16x16x32_bf16(ah[m], bh, acc[m][n], 0, 0, 0);
        acc[m][n] = __builtin_amdgcn_mfma_f32_16x16x32_bf16(ah[m], bl, acc[m][n], 0, 0, 0);
        acc[m][n] = __builtin_amdgcn_mfma_f32_16x16x32_bf16(al[m], bh, acc[m][n], 0, 0, 0);
      }
    }
    __syncthreads();
  }
  int drow = (l >> 4) * 4, dcol = l & 15;
#pragma unroll
  for (int m = 0; m < 4; ++m)
#pragma unroll
    for (int n = 0; n < 4; ++n)
#pragma unroll
      for (int j = 0; j < 4; ++j)
        Cw[(size_t)(brow + wr + m * 16 + drow + j) * N + bcol + wc + n * 16 + dcol] =
            acc[m][n][j];
}

// ---------------------------------------------------------------------------
// part[slice][M=4096][80] = u[.,kslice] . xp[.,kslice]^T  (split-K, no atomics)
// ---------------------------------------------------------------------------
__global__ __launch_bounds__(256) void xproj_gemm(
    const float* __restrict__ u, const float* __restrict__ xp,
    float* __restrict__ part) {
  const int BM = 64, BK = 32;
  __shared__ __align__(16) float As[BK][BM + 4];   // stride 68 (16B-aligned)
  __shared__ float Bs[BK][DBC_W + 1];              // stride 81
  int brow = blockIdx.x * BM;
  int kbase = blockIdx.y * XP_KSL;
  int tid = threadIdx.x;
  int tr = (tid / 16) * 4;    // 0..60
  int tc = (tid % 16) * 5;    // 0..75
  float acc[4][5] = {};
  for (int k0 = kbase; k0 < kbase + XP_KSL; k0 += BK) {
#pragma unroll
    for (int it = 0; it < 2; ++it) {           // A: 64 rows x 32 k
      int lin = tid + it * 256;                // 0..511
      int r  = lin >> 3;                       // 0..63
      int kq = (lin & 7) * 4;
      float4 a = *(const float4*)&u[(size_t)(brow + r) * D_INNER + k0 + kq];
      As[kq + 0][r] = a.x; As[kq + 1][r] = a.y;
      As[kq + 2][r] = a.z; As[kq + 3][r] = a.w;
    }
#pragma unroll
    for (int it = 0; it < 3; ++it) {           // B: 80 rows x 32 k
      int lin = tid + it * 256;                // 0..767 (need < 640)
      if (lin < 640) {
        int e  = lin >> 3;                     // 0..79
        int kq = (lin & 7) * 4;
        float4 bv = *(const float4*)&xp[(size_t)e * D_INNER + k0 + kq];
        Bs[kq + 0][e] = bv.x; Bs[kq + 1][e] = bv.y;
        Bs[kq + 2][e] = bv.z; Bs[kq + 3][e] = bv.w;
      }
    }
    __syncthreads();
#pragma unroll
    for (int kk = 0; kk < BK; ++kk) {
      float4 av = *(const float4*)&As[kk][tr];
      float ar[4] = {av.x, av.y, av.z, av.w};
      float br[5];
#pragma unroll
      for (int j = 0; j < 5; ++j) br[j] = Bs[kk][tc + j];
#pragma unroll
      for (int i = 0; i < 4; ++i)
#pragma unroll
        for (int j = 0; j < 5; ++j) acc[i][j] += ar[i] * br[j];
    }
    __syncthreads();
  }
  float* dst = part + (size_t)blockIdx.y * NTOK * DBC_W;
#pragma unroll
  for (int i = 0; i < 4; ++i)
#pragma unroll
    for (int j = 0; j < 5; ++j)
      dst[(size_t)(brow + tr + i) * DBC_W + tc + j] = acc[i][j];
}

// ---------------------------------------------------------------------------
// dbc = sum over XP_KS slices of part.  float4-vectorized.
// ---------------------------------------------------------------------------
__global__ __launch_bounds__(256) void reduce_dbc_kernel(
    const float* __restrict__ part, float* __restrict__ dbc, int n4) {
  int i = blockIdx.x * 256 + threadIdx.x;
  if (i >= n4) return;
  float4 s = ((const float4*)part)[i];
#pragma unroll
  for (int k = 1; k < XP_KS; ++k) {
    float4 v = ((const float4*)(part + (size_t)k * NTOK * DBC_W))[i];
    s.x += v.x; s.y += v.y; s.z += v.z; s.w += v.w;
  }
  ((float4*)dbc)[i] = s;
}

// ---------------------------------------------------------------------------
// Causal depthwise conv (width 4) + bias + SiLU, rolling-window form.
// ---------------------------------------------------------------------------
__global__ __launch_bounds__(256) void conv_silu_kernel(
    const float* __restrict__ xz, const float* __restrict__ cw,
    const float* __restrict__ cb, float* __restrict__ u) {
  int idx = blockIdx.x * 256 + threadIdx.x;
  const int NTC = SEQLEN / CONV_TCH;
  if (idx >= BATCH * NTC * D_INNER) return;
  int c  = idx % D_INNER;
  int tc = (idx / D_INNER) % NTC;
  int b  = idx / (D_INNER * NTC);
  int t0 = tc * CONV_TCH;
  float w0 = cw[c * 4 + 0], w1 = cw[c * 4 + 1];
  float w2 = cw[c * 4 + 2], w3 = cw[c * 4 + 3];
  float bias = cb[c];
  const float* base = xz + (size_t)b * SEQLEN * (2 * D_INNER) + c;
  float xm3 = 0.f, xm2 = 0.f, xm1 = 0.f;
  if (t0 > 0) {
    xm3 = base[(size_t)(t0 - 3) * (2 * D_INNER)];
    xm2 = base[(size_t)(t0 - 2) * (2 * D_INNER)];
    xm1 = base[(size_t)(t0 - 1) * (2 * D_INNER)];
  }
  float* ub = u + (size_t)(b * SEQLEN + t0) * D_INNER + c;
#pragma unroll
  for (int i = 0; i < CONV_TCH; ++i) {
    float xt = base[(size_t)(t0 + i) * (2 * D_INNER)];
    float acc = bias + xm3 * w0 + xm2 * w1 + xm1 * w2 + xt * w3;
    float sig = 1.f / (1.f + __expf(-acc));
    ub[(size_t)i * D_INNER] = acc * sig;
    xm3 = xm2; xm2 = xm1; xm1 = xt;
  }
}

__device__ __forceinline__ float softplusf(float a) {
  return (a > 20.f) ? a : log1pf(__expf(a));
}

// ---------------------------------------------------------------------------
// Blocked selective scan, phase 1, with dt-projection FUSED.
// Each thread holds dt_w[d, 0:48] in VGPRs (295 KB table, L2-resident) and
// computes dtv = softplus(dot(dbc[row,0:48], w) + bias) on the fly.  The
// activated dtv is STORED to dty so scan_chunk2 reads it directly -- the
// K=48 dt-GEMM kernel is eliminated.  b,c derived from blockIdx only
// (wave-uniform dbc row address -> s_load).
// ---------------------------------------------------------------------------
__global__ __launch_bounds__(256) void scan_chunk1(
    float* __restrict__ dty, const float* __restrict__ u,
    const float* __restrict__ dbc, const float* __restrict__ A_log,
    const float* __restrict__ dtw, const float* __restrict__ dtb,
    float* __restrict__ S, float* __restrict__ dtsum) {
  int blk = blockIdx.x;                      // 0 .. BATCH*NC*D_INNER/256-1
  int bcq = (blk * 256) / D_INNER;           // uniform: b*NC + c
  int d = blk * 256 - bcq * D_INNER + threadIdx.x;
  int c = bcq & (NC - 1);
  int b = bcq / NC;
  float A[D_STATE];
#pragma unroll
  for (int s = 0; s < D_STATE; ++s) A[s] = -__expf(A_log[d * D_STATE + s]);
  float w[DT_RANK];
  {
    const float4* w4 = (const float4*)(dtw + (size_t)d * DT_RANK);
#pragma unroll
    for (int j = 0; j < DT_RANK / 4; ++j) {
      float4 v = w4[j];
      w[j * 4 + 0] = v.x; w[j * 4 + 1] = v.y;
      w[j * 4 + 2] = v.z; w[j * 4 + 3] = v.w;
    }
  }
  float bias = dtb[d];
  float h[D_STATE];
#pragma unroll
  for (int s = 0; s < D_STATE; ++s) h[s] = 0.f;
  float dts = 0.f;
  int t0 = c * CHUNK_T;
  for (int t = t0; t < t0 + CHUNK_T; ++t) {
    size_t rowb = (size_t)b * SEQLEN + t;    // uniform
    const float* bc = dbc + rowb * DBC_W;    // uniform address -> s_load
    float raw = bias;
#pragma unroll
    for (int k = 0; k < DT_RANK; ++k) raw += bc[k] * w[k];
    float dtv = softplusf(raw);
    dty[rowb * D_INNER + d] = dtv;           // for scan_chunk2
    float uv  = u[rowb * D_INNER + d];
    float dtu = dtv * uv;
    dts += dtv;
#pragma unroll
    for (int s = 0; s < D_STATE; ++s) {
      float da = __expf(dtv * A[s]);
      h[s] = da * h[s] + dtu * bc[DT_RANK + s];
    }
  }
  size_t base = (((size_t)b * NC + c) * D_STATE) * D_INNER + d;
#pragma unroll
  for (int s = 0; s < D_STATE; ++s) S[base + (size_t)s * D_INNER] = h[s];
  dtsum[((size_t)b * NC + c) * D_INNER + d] = dts;
}

// ---------------------------------------------------------------------------
// Blocked selective scan, phase 2 (serial chunk combine).
// One thread per (b, s, d).
// ---------------------------------------------------------------------------
__global__ __launch_bounds__(256) void scan_combine(
    float* __restrict__ S, const float* __restrict__ dtsum,
    const float* __restrict__ A_log) {
  int g = blockIdx.x * 256 + threadIdx.x;
  if (g >= BATCH * D_STATE * D_INNER) return;
  int d = g % D_INNER;
  int s = (g / D_INNER) % D_STATE;
  int b = g / (D_INNER * D_STATE);
  float A = -__expf(A_log[d * D_STATE + s]);
  float h = 0.f;
  for (int c = 0; c < NC; ++c) {
    size_t off = (((size_t)b * NC + c) * D_STATE + s) * D_INNER + d;
    float dts = dtsum[((size_t)b * NC + c) * D_INNER + d];
    float Sv = S[off];
    S[off] = h;                          // h_in for chunk c
    h = __expf(dts * A) * h + Sv;
  }
}

// ---------------------------------------------------------------------------
// Blocked selective scan, phase 3.  dty now holds the ACTIVATED dt from
// scan_chunk1 (no bias/softplus here).
// ---------------------------------------------------------------------------
__global__ __launch_bounds__(256) void scan_chunk2(
    const float* __restrict__ dty, const float* __restrict__ u,
    const float* __restrict__ dbc, const float* __restrict__ xz,
    const float* __restrict__ A_log,
    const float* __restrict__ Dv, const float* __restrict__ hin,
    short* __restrict__ y_hi, short* __restrict__ y_lo) {
  int blk = blockIdx.x;
  int bcq = (blk * 256) / D_INNER;           // uniform: b*NC + c
  int d = blk * 256 - bcq * D_INNER + threadIdx.x;
  int c = bcq & (NC - 1);
  int b = bcq / NC;
  float A[D_STATE];
#pragma unroll
  for (int s = 0; s < D_STATE; ++s) A[s] = -__expf(A_log[d * D_STATE + s]);
  float Dval = Dv[d];
  float h[D_STATE];
  size_t hbase = (((size_t)b * NC + c) * D_STATE) * D_INNER + d;
#pragma unroll
  for (int s = 0; s < D_STATE; ++s) h[s] = hin[hbase + (size_t)s * D_INNER];
  int t0 = c * CHUNK_T;
  for (int t = t0; t < t0 + CHUNK_T; ++t) {
    size_t rowb = (size_t)b * SEQLEN + t;    // uniform
    const float* bc = dbc + rowb * DBC_W;    // uniform address -> s_load
    float dtv = dty[rowb * D_INNER + d];     // already softplus'd
    float uv  = u[rowb * D_INNER + d];
    float dtu = dtv * uv;
    float yv = 0.f;
#pragma unroll
    for (int s = 0; s < D_STATE; ++s) {
      float da = __expf(dtv * A[s]);
      h[s] = da * h[s] + dtu * bc[DT_RANK + s];
      yv += h[s] * bc[DT_RANK + D_STATE + s];
    }
    float zv = xz[rowb * (2 * D_INNER) + D_INNER + d];
    float sig = 1.f / (1.f + __expf(-zv));
    float yo = (yv + uv * Dval) * (zv * sig);
    short hv, lv; split_bf16(yo, hv, lv);
    y_hi[rowb * D_INNER + d] = hv;
    y_lo[rowb * D_INNER + d] = lv;
  }
}

// ---------------------------------------------------------------------------
// Final: out_proj partial-sum + residual add + LN(normf) + LN(dec),
// last rtn tokens only.  (reduce_out fused here too.)
// ---------------------------------------------------------------------------
__global__ __launch_bounds__(256) void final_kernel(
    const float* __restrict__ opart, const float* __restrict__ resid,
    const float* __restrict__ fw, const float* __restrict__ fb,
    const float* __restrict__ dw, const float* __restrict__ db,
    float* __restrict__ out, int rtn) {
  int rowo = blockIdx.x;                 // 0 .. BATCH*rtn-1
  int b = rowo / rtn;
  int t = SEQLEN - rtn + (rowo % rtn);
  int tid = threadIdx.x;
  size_t base = ((size_t)b * SEQLEN + t) * D_MODEL;
  __shared__ float red[256];
  __shared__ float s_mu1, s_rs1, s_mu2, s_rs2;
  float v[3];
#pragma unroll
  for (int i = 0; i < 3; ++i) {
    int c = tid + i * 256;
    float hysum = opart[base + c];
#pragma unroll
    for (int k = 1; k < OP_KS; ++k)
      hysum += opart[(size_t)k * NTOK * D_MODEL + base + c];
    v[i] = hysum + resid[base + c];
  }
  // --- LN 1 ---
  red[tid] = v[0] + v[1] + v[2]; __syncthreads();
  for (int off = 128; off > 0; off >>= 1) {
    if (tid < off) red[tid] += red[tid + off];
    __syncthreads();
  }
  if (tid == 0) s_mu1 = red[0] / D_MODEL;
  __syncthreads();
  float mu = s_mu1, q = 0.f;
#pragma unroll
  for (int i = 0; i < 3; ++i) { float dd = v[i] - mu; q += dd * dd; }
  __syncthreads();
  red[tid] = q; __syncthreads();
  for (int off = 128; off > 0; off >>= 1) {
    if (tid < off) red[tid] += red[tid + off];
    __syncthreads();
  }
  if (tid == 0) s_rs1 = rsqrtf(red[0] / D_MODEL + 1e-5f);
  __syncthreads();
  float rs = s_rs1;
#pragma unroll
  for (int i = 0; i < 3; ++i) {
    int c = tid + i * 256;
    v[i] = (v[i] - mu) * rs * fw[c] + fb[c];
  }
  // --- LN 2 ---
  __syncthreads();
  red[tid] = v[0] + v[1] + v[2]; __syncthreads();
  for (int off = 128; off > 0; off >>= 1) {
    if (tid < off) red[tid] += red[tid + off];
    __syncthreads();
  }
  if (tid == 0) s_mu2 = red[0] / D_MODEL;
  __syncthreads();
  mu = s_mu2; q = 0.f;
#pragma unroll
  for (int i = 0; i < 3; ++i) { float dd = v[i] - mu; q += dd * dd; }
  __syncthreads();
  red[tid] = q; __syncthreads();
  for (int off = 128; off > 0; off >>= 1) {
    if (tid < off) red[tid] += red[tid + off];
    __syncthreads();
  }
  if (tid == 0) s_rs2 = rsqrtf(red[0] / D_MODEL + 1e-5f);
  __syncthreads();
  rs = s_rs2;
#pragma unroll
  for (int i = 0; i < 3; ++i) {
    int c = tid + i * 256;
    out[(size_t)rowo * D_MODEL + c] = (v[i] - mu) * rs * dw[c] + db[c];
  }
}

// ---------------------------------------------------------------------------
extern "C" void kernel_launch(void* const* d_in, const int* in_sizes, int n_in,
                              void* d_out, int out_size, void* d_ws, size_t ws_size,
                              hipStream_t stream) {
  const float* x       = (const float*)d_in[0];
  const float* pos     = (const float*)d_in[1];
  const float* norm_w  = (const float*)d_in[2];
  const float* norm_b  = (const float*)d_in[3];
  const float* in_proj = (const float*)d_in[4];
  const float* conv_w  = (const float*)d_in[5];
  const float* conv_b  = (const float*)d_in[6];
  const float* x_proj  = (const float*)d_in[7];
  const float* dt_w    = (const float*)d_in[8];
  const float* dt_b    = (const float*)d_in[9];
  const float* A_log   = (const float*)d_in[10];
  const float* Dv      = (const float*)d_in[11];
  const float* out_proj= (const float*)d_in[12];
  const float* normf_w = (const float*)d_in[13];
  const float* normf_b = (const float*)d_in[14];
  const float* dec_w   = (const float*)d_in[15];
  const float* dec_b   = (const float*)d_in[16];
  int rtn = out_size / (BATCH * D_MODEL);   // return_token_num

  const size_t WI = (size_t)2 * D_INNER * D_MODEL;   // in_proj elems / layer
  const size_t WO = (size_t)D_MODEL * D_INNER;       // out_proj elems / layer

  float* ws    = (float*)d_ws;
  float* resid = ws;                                 // NTOK*D_MODEL
  float* xz    = resid + (size_t)NTOK * D_MODEL;     // NTOK*2*D_INNER (also opart)
  float* u     = xz    + (size_t)NTOK * 2 * D_INNER; // NTOK*D_INNER
  float* dbc   = u     + (size_t)NTOK * D_INNER;     // NTOK*80
  float* dty   = dbc   + (size_t)NTOK * DBC_W;       // NTOK*D_INNER (softplus dt)
  float* Sbuf  = dty   + (size_t)NTOK * D_INNER;     // BATCH*NC*D_STATE*D_INNER
  float* dtsum = Sbuf  + (size_t)BATCH * NC * D_STATE * D_INNER; // BATCH*NC*D_INNER
  // dbcp (XP_KS*NTOK*80 = 21.0 MB) aliases Sbuf (25.2 MB): xproj+reduce_dbc
  // finish before scan_chunk1 writes S.
  float* dbcp  = Sbuf;
  short* hh_hi = (short*)(dtsum + (size_t)BATCH * NC * D_INNER);
  short* hh_lo = hh_hi + (size_t)NTOK * D_MODEL;
  short* y_hi  = hh_lo + (size_t)NTOK * D_MODEL;
  short* y_lo  = y_hi  + (size_t)NTOK * D_INNER;
  short* wIh   = y_lo  + (size_t)NTOK * D_INNER;     // 8 layers in_proj hi
  short* wIl   = wIh + N_LAYER * WI;                 // 8 layers in_proj lo
  short* wOh   = wIl + N_LAYER * WI;                 // 8 layers out_proj hi
  short* wOl   = wOh + N_LAYER * WO;                 // 8 layers out_proj lo
  float* opart = xz;   // out_proj split-K partials reuse xz (z dead by then)

  // Hoisted weight splits: all layers at once (weights are layer-constant).
  split_kernel<<<2048, 256, 0, stream>>>(in_proj, wIh, wIl,
                                         (int)(N_LAYER * WI / 4));
  split_kernel<<<2048, 256, 0, stream>>>(out_proj, wOh, wOl,
                                         (int)(N_LAYER * WO / 4));

  for (int l = 0; l < N_LAYER; ++l) {
    ln_kernel<<<NTOK, 256, 0, stream>>>(x, pos, resid, opart, hh_hi, hh_lo,
        norm_w + l * D_MODEL, norm_b + l * D_MODEL, l == 0);

    dim3 g1(2 * D_INNER / 128, NTOK / 128, 1);
    gemm_bf16x3<<<g1, 256, 0, stream>>>(hh_hi, hh_lo, D_MODEL,
        wIh + l * WI, wIl + l * WI, D_MODEL, xz, NTOK, 2 * D_INNER, D_MODEL);

    int convtot = BATCH * (SEQLEN / CONV_TCH) * D_INNER;
    conv_silu_kernel<<<(convtot + 255) / 256, 256, 0, stream>>>(
        xz, conv_w + (size_t)l * D_INNER * D_CONV, conv_b + l * D_INNER, u);

    dim3 gxp(NTOK / 64, XP_KS);
    xproj_gemm<<<gxp, 256, 0, stream>>>(
        u, x_proj + (size_t)l * DBC_W * D_INNER, dbcp);
    reduce_dbc_kernel<<<(NTOK * DBC_W / 4 + 255) / 256, 256, 0, stream>>>(
        dbcp, dbc, NTOK * DBC_W / 4);

    const float* Al = A_log + (size_t)l * D_INNER * D_STATE;
    int tot1 = BATCH * NC * D_INNER;
    scan_chunk1<<<tot1 / 256, 256, 0, stream>>>(
        dty, u, dbc, Al, dt_w + (size_t)l * D_INNER * DT_RANK,
        dt_b + (size_t)l * D_INNER, Sbuf, dtsum);
    scan_combine<<<(BATCH * D_STATE * D_INNER + 255) / 256, 256, 0, stream>>>(
        Sbuf, dtsum, Al);
    scan_chunk2<<<tot1 / 256, 256, 0, stream>>>(
        dty, u, dbc, xz, Al, Dv + l * D_INNER, Sbuf, y_hi, y_lo);

    // out_proj split-K=4: partials into opart (reused xz); reduction fused
    // into next layer's ln_kernel / final_kernel.
    dim3 g2(D_MODEL / 128, NTOK / 128, OP_KS);
    gemm_bf16x3<<<g2, 256, 0, stream>>>(y_hi, y_lo, D_INNER,
        wOh + l * WO, wOl + l * WO, D_INNER, opart, NTOK, D_MODEL, D_INNER);
  }

  final_kernel<<<BATCH * rtn, 256, 0, stream>>>(
      opart, resid, normf_w, normf_b, dec_w, dec_b, (float*)d_out, rtn);
}